// Round 1
// baseline (3163.998 us; speedup 1.0000x reference)
//
#include <hip/hip_runtime.h>

#define NN 20000
#define EE 400000
#define DD 256
#define RSBN 0.9999950000374997f   // 1/sqrt(1+1e-5)
#define TE 16

// ---------------- edge parser + edge weight ----------------
__global__ __launch_bounds__(256, 1) void edge_kernel(
    const float* __restrict__ xin, const int* __restrict__ eidx,
    const float* __restrict__ w1, const float* __restrict__ b1,
    const float* __restrict__ g1, const float* __restrict__ be1,
    const float* __restrict__ w2, const float* __restrict__ b2,
    float* __restrict__ ew_out, float* __restrict__ ew_ws,
    float* __restrict__ deg, int* __restrict__ cnt)
{
  __shared__ float xs[TE * 64];
  __shared__ float as_[TE * 2 * 128];
  __shared__ float hs[TE * 2 * 128];
  int tid = threadIdx.x;
  int h = tid >> 7;      // which half (parser input)
  int j = tid & 127;     // output channel

  float w1r[32], w2r[128];
#pragma unroll
  for (int k = 0; k < 32; k++) w1r[k] = w1[k * 128 + j];
#pragma unroll
  for (int k = 0; k < 128; k++) w2r[k] = w2[k * 128 + j];
  float b1j = b1[j], s1j = g1[j] * RSBN, be1j = be1[j], b2j = b2[j];

  int base = blockIdx.x * TE;
  // stage TE edges' inputs (TE*64 floats = 256 float4)
  ((float4*)xs)[tid] = ((const float4*)(xin + (size_t)base * 64))[tid];
  __syncthreads();

  // phase A: a = BN(relu(x @ W1 + b1))
#pragma unroll 1
  for (int e = 0; e < TE; e++) {
    const float* xp = xs + e * 64 + h * 32;
    float a0 = 0.f, a1 = 0.f;
#pragma unroll
    for (int k = 0; k < 32; k += 8) {
      float4 v0 = *(const float4*)(xp + k);
      float4 v1 = *(const float4*)(xp + k + 4);
      a0 += v0.x * w1r[k]     + v0.y * w1r[k + 1] + v0.z * w1r[k + 2] + v0.w * w1r[k + 3];
      a1 += v1.x * w1r[k + 4] + v1.y * w1r[k + 5] + v1.z * w1r[k + 6] + v1.w * w1r[k + 7];
    }
    float a = fmaxf(a0 + a1 + b1j, 0.f) * s1j + be1j;
    as_[(e * 2 + h) * 128 + j] = a;
  }
  __syncthreads();

  // phase B: hout = a @ W2 + b2
#pragma unroll 1
  for (int e = 0; e < TE; e++) {
    const float* ap = as_ + (e * 2 + h) * 128;
    float a0 = 0.f, a1 = 0.f;
#pragma unroll
    for (int k = 0; k < 128; k += 8) {
      float4 v0 = *(const float4*)(ap + k);
      float4 v1 = *(const float4*)(ap + k + 4);
      a0 += v0.x * w2r[k]     + v0.y * w2r[k + 1] + v0.z * w2r[k + 2] + v0.w * w2r[k + 3];
      a1 += v1.x * w2r[k + 4] + v1.y * w2r[k + 5] + v1.z * w2r[k + 6] + v1.w * w2r[k + 7];
    }
    hs[(e * 2 + h) * 128 + j] = a0 + a1 + b2j;
  }
  __syncthreads();

  // reduction: cosine sim per edge (16 lanes per edge)
  int e = tid >> 4, l = tid & 15;
  const float* h1 = hs + e * 256;
  const float* h2 = h1 + 128;
  float p = 0.f, q = 0.f, r = 0.f;
#pragma unroll
  for (int k0 = 0; k0 < 8; k0++) {
    float v1 = h1[l * 8 + k0], v2 = h2[l * 8 + k0];
    p += v1 * v2; q += v1 * v1; r += v2 * v2;
  }
#pragma unroll
  for (int m = 1; m < 16; m <<= 1) {
    p += __shfl_xor(p, m, 64);
    q += __shfl_xor(q, m, 64);
    r += __shfl_xor(r, m, 64);
  }
  if (l == 0) {
    float n1 = fmaxf(sqrtf(q), 1e-8f);
    float n2 = fmaxf(sqrtf(r), 1e-8f);
    float w = (p / (n1 * n2) + 1.f) * 0.5f;
    int ge = base + e;
    ew_out[ge] = w;
    ew_ws[ge] = w;
    atomicAdd(deg + eidx[ge], w);
    atomicAdd(cnt + eidx[EE + ge], 1);
  }
}

// ---------------- degree -> D^-1/2 ----------------
__global__ void dis_kernel(const float* __restrict__ deg, float* __restrict__ dis) {
  int i = blockIdx.x * 256 + threadIdx.x;
  if (i < NN) {
    float d = deg[i];
    dis[i] = d > 0.f ? 1.f / sqrtf(fmaxf(d, 1e-30f)) : 0.f;
  }
}

// ---------------- exclusive scan of in-degree counts ----------------
__global__ __launch_bounds__(1024) void scan_kernel(const int* __restrict__ cnt, int* __restrict__ ptr) {
  __shared__ int sums[1024];
  int tid = threadIdx.x;
  const int n = NN;
  const int chunk = (n + 1023) / 1024;
  int base = tid * chunk;
  int s = 0;
  for (int i = 0; i < chunk; i++) { int idx = base + i; if (idx < n) s += cnt[idx]; }
  sums[tid] = s;
  __syncthreads();
  for (int off = 1; off < 1024; off <<= 1) {
    int v = (tid >= off) ? sums[tid - off] : 0;
    __syncthreads();
    sums[tid] += v;
    __syncthreads();
  }
  int run = (tid == 0) ? 0 : sums[tid - 1];
  for (int i = 0; i < chunk; i++) {
    int idx = base + i;
    if (idx < n) { ptr[idx] = run; run += cnt[idx]; }
  }
  if (tid == 1023) ptr[n] = run;
}

// ---------------- CSR fill (by destination col), value = -dis[row]*ew*dis[col] ----------------
__global__ void fill_kernel(const int* __restrict__ eidx, const float* __restrict__ ew,
                            const float* __restrict__ dis, const int* __restrict__ ptr,
                            int* __restrict__ fill, int* __restrict__ cidx, float* __restrict__ cval) {
  int e = blockIdx.x * 256 + threadIdx.x;
  if (e < EE) {
    int r = eidx[e], c = eidx[EE + e];
    float nv = -dis[r] * ew[e] * dis[c];
    int pos = ptr[c] + atomicAdd(&fill[c], 1);
    cidx[pos] = r;
    cval[pos] = nv;
  }
}

// ---------------- sparse prop: y[c] = alpha * sum_e val*x[row]  (- sub[c]) ----------------
__global__ __launch_bounds__(256) void prop_kernel(
    const float* __restrict__ x, int ldx,
    const int* __restrict__ cidx, const float* __restrict__ cval,
    const int* __restrict__ ptr,
    float* __restrict__ y, int ldy,
    float alpha, const float* __restrict__ sub, int ldsub)
{
  int c = blockIdx.x * 4 + (threadIdx.x >> 6);
  if (c >= NN) return;
  int lane = threadIdx.x & 63;
  int d = lane * 4;
  int p0 = ptr[c], p1 = ptr[c + 1];
  float ax = 0.f, ay = 0.f, az = 0.f, aw = 0.f;
  int p = p0;
  for (; p + 1 < p1; p += 2) {
    int r0 = cidx[p], r1 = cidx[p + 1];
    float w0 = cval[p], w1v = cval[p + 1];
    float4 v0 = *(const float4*)(x + (size_t)r0 * ldx + d);
    float4 v1 = *(const float4*)(x + (size_t)r1 * ldx + d);
    ax += w0 * v0.x + w1v * v1.x;
    ay += w0 * v0.y + w1v * v1.y;
    az += w0 * v0.z + w1v * v1.z;
    aw += w0 * v0.w + w1v * v1.w;
  }
  if (p < p1) {
    int r0 = cidx[p]; float w0 = cval[p];
    float4 v0 = *(const float4*)(x + (size_t)r0 * ldx + d);
    ax += w0 * v0.x; ay += w0 * v0.y; az += w0 * v0.z; aw += w0 * v0.w;
  }
  float4 o;
  if (sub) {
    float4 s = *(const float4*)(sub + (size_t)c * ldsub + d);
    o.x = alpha * ax - s.x; o.y = alpha * ay - s.y;
    o.z = alpha * az - s.z; o.w = alpha * aw - s.w;
  } else {
    o.x = ax; o.y = ay; o.z = az; o.w = aw;
  }
  *(float4*)(y + (size_t)c * ldy + d) = o;
}

// ---------------- tiled fp32 GEMM: C = post( sum_c A_c @ B[c*256..] ) ----------------
// post: +bias (opt), relu, BN scale/shift (opt). B row-major (nchunks*256) x 256.
__global__ __launch_bounds__(256) void gemm_kernel(
    const float* A0, const float* A1, const float* A2, const float* A3,
    int l0, int l1, int l2, int l3, int nchunks,
    const float* __restrict__ B,
    float* __restrict__ C, int ldc, int M,
    const float* __restrict__ bias, const float* __restrict__ bng, const float* __restrict__ bnb)
{
  __shared__ float As[16][68];
  __shared__ float Bs[16][64];
  int tid = threadIdx.x;
  int tx = tid & 15, ty = tid >> 4;
  int m0 = blockIdx.x * 64;
  int n0 = blockIdx.y * 64;
  float acc[4][4] = {};
  const float* Ap[4] = {A0, A1, A2, A3};
  int Al[4] = {l0, l1, l2, l3};
  int arow = tid >> 2;
  int akq = (tid & 3) * 4;
  int brow = tid >> 4;
  int bcol = (tid & 15) * 4;
  bool aval = (m0 + arow) < M;

  for (int c = 0; c < nchunks; c++) {
    const float* A = Ap[c];
    int lda = Al[c];
    const float* Arow = A + (size_t)(m0 + arow) * lda;
    for (int kb = 0; kb < 256; kb += 16) {
      float4 av = aval ? *(const float4*)(Arow + kb + akq) : make_float4(0.f, 0.f, 0.f, 0.f);
      float4 bv = *(const float4*)(B + (size_t)(c * 256 + kb + brow) * 256 + n0 + bcol);
      __syncthreads();
      As[akq + 0][arow] = av.x;
      As[akq + 1][arow] = av.y;
      As[akq + 2][arow] = av.z;
      As[akq + 3][arow] = av.w;
      *(float4*)&Bs[brow][bcol] = bv;
      __syncthreads();
#pragma unroll
      for (int k = 0; k < 16; k++) {
        float4 a4 = *(const float4*)&As[k][ty * 4];
        float4 b4 = *(const float4*)&Bs[k][tx * 4];
        float avv[4] = {a4.x, a4.y, a4.z, a4.w};
        float bvv[4] = {b4.x, b4.y, b4.z, b4.w};
#pragma unroll
        for (int i = 0; i < 4; i++)
#pragma unroll
          for (int jj = 0; jj < 4; jj++)
            acc[i][jj] += avv[i] * bvv[jj];
      }
    }
  }

#pragma unroll
  for (int i = 0; i < 4; i++) {
    int m = m0 + ty * 4 + i;
    if (m < M) {
#pragma unroll
      for (int jj = 0; jj < 4; jj++) {
        int n = n0 + tx * 4 + jj;
        float v = acc[i][jj];
        if (bias) v += bias[n];
        v = fmaxf(v, 0.f);
        if (bng) v = v * (bng[n] * RSBN) + bnb[n];
        C[(size_t)m * ldc + n] = v;
      }
    }
  }
}

// ---------------- final 256x2 matvec per node ----------------
__global__ __launch_bounds__(256) void logit_kernel(
    const float* __restrict__ z, const float* __restrict__ w2,
    const float* __restrict__ b2, float* __restrict__ out)
{
  int node = blockIdx.x * 4 + (threadIdx.x >> 6);
  if (node >= NN) return;
  int lane = threadIdx.x & 63;
  int k = lane * 4;
  float4 zv = *(const float4*)(z + (size_t)node * 256 + k);
  float4 wa = *(const float4*)(w2 + k * 2);
  float4 wb = *(const float4*)(w2 + k * 2 + 4);
  float a0 = zv.x * wa.x + zv.y * wa.z + zv.z * wb.x + zv.w * wb.z;
  float a1 = zv.x * wa.y + zv.y * wa.w + zv.z * wb.y + zv.w * wb.w;
#pragma unroll
  for (int m = 32; m >= 1; m >>= 1) {
    a0 += __shfl_xor(a0, m, 64);
    a1 += __shfl_xor(a1, m, 64);
  }
  if (lane == 0) {
    out[(size_t)node * 2]     = a0 + b2[0];
    out[(size_t)node * 2 + 1] = a1 + b2[1];
  }
}

extern "C" void kernel_launch(void* const* d_in, const int* in_sizes, int n_in,
                              void* d_out, int out_size, void* d_ws, size_t ws_size,
                              hipStream_t stream) {
  const float* features = (const float*)d_in[0];
  const int*   eidx     = (const int*)d_in[1];
  const float* xin      = (const float*)d_in[2];
  const float* cheb_w   = (const float*)d_in[3];
  const float* en_w1    = (const float*)d_in[4];
  const float* en_b1    = (const float*)d_in[5];
  const float* en_g1    = (const float*)d_in[6];
  const float* en_be1   = (const float*)d_in[7];
  const float* en_w2    = (const float*)d_in[8];
  const float* en_b2    = (const float*)d_in[9];
  const float* cls_w1   = (const float*)d_in[10];
  const float* cls_b1   = (const float*)d_in[11];
  const float* cls_g    = (const float*)d_in[12];
  const float* cls_b    = (const float*)d_in[13];
  const float* cls_w2   = (const float*)d_in[14];
  const float* cls_b2   = (const float*)d_in[15];
  float* out = (float*)d_out;

  char* ws = (char*)d_ws;
  size_t off = 0;
  auto alloc = [&](size_t bytes) -> void* {
    void* p = ws + off;
    off += (bytes + 255) & ~(size_t)255;
    return p;
  };
  float* deg  = (float*)alloc((size_t)NN * 4);
  int*   cnt  = (int*)  alloc((size_t)NN * 4);
  int*   fil  = (int*)  alloc((size_t)NN * 4);
  size_t zero_len = off;                       // deg+cnt+fil zeroed in one memset
  float* dis  = (float*)alloc((size_t)NN * 4);
  int*   ptr  = (int*)  alloc((size_t)(NN + 1) * 4);
  float* ew   = (float*)alloc((size_t)EE * 4);
  int*   cidx = (int*)  alloc((size_t)EE * 4);
  float* cval = (float*)alloc((size_t)EE * 4);
  float* Tx1  = (float*)alloc((size_t)NN * 256 * 4);
  float* Tx2  = (float*)alloc((size_t)NN * 256 * 4);
  float* zbuf = (float*)alloc((size_t)NN * 256 * 4);
  float* jk   = (float*)alloc((size_t)NN * 1024 * 4);

  hipMemsetAsync(deg, 0, zero_len, stream);

  // edge weights + degree + in-degree counts
  edge_kernel<<<EE / TE, 256, 0, stream>>>(xin, eidx, en_w1, en_b1, en_g1, en_be1,
                                           en_w2, en_b2, out + (size_t)NN * 2, ew, deg, cnt);
  dis_kernel<<<(NN + 255) / 256, 256, 0, stream>>>(deg, dis);
  scan_kernel<<<1, 1024, 0, stream>>>(cnt, ptr);
  fill_kernel<<<(EE + 255) / 256, 256, 0, stream>>>(eidx, ew, dis, ptr, fil, cidx, cval);

  dim3 ggrid(313, 4);
  for (int i = 0; i < 4; i++) {
    const float* x = (i == 0) ? features : (jk + (size_t)(i - 1) * 256);
    int ldx = (i == 0) ? 256 : 1024;
    prop_kernel<<<NN / 4, 256, 0, stream>>>(x, ldx, cidx, cval, ptr, Tx1, 256, 1.f, nullptr, 0);
    prop_kernel<<<NN / 4, 256, 0, stream>>>(Tx1, 256, cidx, cval, ptr, Tx2, 256, 2.f, x, ldx);
    gemm_kernel<<<ggrid, 256, 0, stream>>>(x, Tx1, Tx2, nullptr, ldx, 256, 256, 0, 3,
                                           cheb_w + (size_t)i * 3 * 256 * 256,
                                           jk + (size_t)i * 256, 1024, NN,
                                           nullptr, nullptr, nullptr);
  }

  // cls head: z = BN(relu(jk @ W1 + b1)), logit = z @ W2 + b2
  gemm_kernel<<<ggrid, 256, 0, stream>>>(jk, jk + 256, jk + 512, jk + 768,
                                         1024, 1024, 1024, 1024, 4,
                                         cls_w1, zbuf, 256, NN,
                                         cls_b1, cls_g, cls_b);
  logit_kernel<<<NN / 4, 256, 0, stream>>>(zbuf, cls_w2, cls_b2, out);
}

// Round 2
// 1330.159 us; speedup vs baseline: 2.3787x; 2.3787x over previous
//
#include <hip/hip_runtime.h>

#define NN 20000
#define EE 400000
#define DD 256
#define RSBN 0.9999950000374997f   // 1/sqrt(1+1e-5)

typedef __attribute__((ext_vector_type(8))) short short8;
typedef __attribute__((ext_vector_type(4))) float floatx4;

__device__ __forceinline__ short f2bf(float f) {
  union { float f; unsigned u; } v; v.f = f;
  unsigned r = v.u + 0x7fffu + ((v.u >> 16) & 1u);   // RNE
  return (short)(r >> 16);
}

// ---------------- edge parser + edge weight (bf16 MFMA) ----------------
// X viewed as (2E, 32): row 2e = half1 of edge e, row 2e+1 = half2.
// Block: 128 rows x 128 cols. 4 waves, each wave 32 rows.
#define ASP 136   // as_s row stride in bf16 (272B, 16B-aligned)
__global__ __launch_bounds__(256, 2) void edge_kernel(
    const float* __restrict__ xin, const int* __restrict__ eidx,
    const float* __restrict__ w1, const float* __restrict__ b1,
    const float* __restrict__ g1, const float* __restrict__ be1,
    const float* __restrict__ w2, const float* __restrict__ b2,
    float* __restrict__ ew_out, float* __restrict__ ew_ws,
    float* __restrict__ deg, int* __restrict__ cnt)
{
  __shared__ short w1f[8 * 64 * 8];        // [ctile][lane][j]
  __shared__ short w2f[4 * 8 * 64 * 8];    // [kstep][ctile][lane][j]
  __shared__ short as_s[128 * ASP];        // activation tile [row][col]

  int tid = threadIdx.x;
  int lane = tid & 63;
  int wv = tid >> 6;
  int l15 = lane & 15;
  int quad = lane >> 4;

  // ---- stage W1 fragments (coalesced read, swizzled LDS write) ----
#pragma unroll
  for (int i = 0; i < 16; i++) {
    int idx = i * 256 + tid;          // k = idx>>7 (0..31), n = idx&127
    int k = idx >> 7, n = idx & 127;
    int pos = ((n >> 4) * 64 + (k >> 3) * 16 + (n & 15)) * 8 + (k & 7);
    w1f[pos] = f2bf(w1[idx]);
  }
  // ---- stage W2 fragments ----
#pragma unroll
  for (int i = 0; i < 64; i++) {
    int idx = i * 256 + tid;          // k = idx>>7 (0..127), n = idx&127
    int k = idx >> 7, n = idx & 127;
    int pos = (((k >> 5) * 8 + (n >> 4)) * 64 + ((k >> 3) & 3) * 16 + (n & 15)) * 8 + (k & 7);
    w2f[pos] = f2bf(w2[idx]);
  }

  // per-lane epilogue constants for cols c*16 + l15
  float b1j[8], s1j[8], be1j[8], b2j[8];
#pragma unroll
  for (int c = 0; c < 8; c++) {
    int n = c * 16 + l15;
    b1j[c] = b1[n]; s1j[c] = g1[n] * RSBN; be1j[c] = be1[n]; b2j[c] = b2[n];
  }

  int rowbase = blockIdx.x * 128 + wv * 32;

  // ---- GEMM1: A fragments straight from global ----
  short8 af[2];
#pragma unroll
  for (int t = 0; t < 2; t++) {
    const float* xp = xin + (size_t)(rowbase + t * 16 + l15) * 32 + quad * 8;
    float4 v0 = *(const float4*)xp;
    float4 v1 = *(const float4*)(xp + 4);
    short8 a;
    a[0] = f2bf(v0.x); a[1] = f2bf(v0.y); a[2] = f2bf(v0.z); a[3] = f2bf(v0.w);
    a[4] = f2bf(v1.x); a[5] = f2bf(v1.y); a[6] = f2bf(v1.z); a[7] = f2bf(v1.w);
    af[t] = a;
  }

  __syncthreads();   // W1/W2 fragments ready

  floatx4 acc[2][8];
#pragma unroll
  for (int t = 0; t < 2; t++)
#pragma unroll
    for (int c = 0; c < 8; c++) {
      floatx4 z = {0.f, 0.f, 0.f, 0.f};
      acc[t][c] = __builtin_amdgcn_mfma_f32_16x16x32_bf16(
          af[t], *(const short8*)&w1f[(c * 64 + lane) * 8], z, 0, 0, 0);
    }

  // ---- epilogue1: relu+BN, write bf16 activation tile (A-layout source) ----
#pragma unroll
  for (int t = 0; t < 2; t++)
#pragma unroll
    for (int c = 0; c < 8; c++)
#pragma unroll
      for (int r = 0; r < 4; r++) {
        float a = fmaxf(acc[t][c][r] + b1j[c], 0.f) * s1j[c] + be1j[c];
        as_s[(wv * 32 + t * 16 + quad * 4 + r) * ASP + c * 16 + l15] = f2bf(a);
      }
  // no __syncthreads needed: each wave reads only its own 32 rows

  // ---- GEMM2: K=128 in 4 steps ----
  floatx4 acc2[2][8];
#pragma unroll
  for (int t = 0; t < 2; t++)
#pragma unroll
    for (int c = 0; c < 8; c++) acc2[t][c] = (floatx4){0.f, 0.f, 0.f, 0.f};
#pragma unroll
  for (int s = 0; s < 4; s++) {
    short8 a2[2];
#pragma unroll
    for (int t = 0; t < 2; t++)
      a2[t] = *(const short8*)&as_s[(wv * 32 + t * 16 + l15) * ASP + s * 32 + quad * 8];
#pragma unroll
    for (int c = 0; c < 8; c++) {
      short8 bf = *(const short8*)&w2f[((s * 8 + c) * 64 + lane) * 8];
#pragma unroll
      for (int t = 0; t < 2; t++)
        acc2[t][c] = __builtin_amdgcn_mfma_f32_16x16x32_bf16(a2[t], bf, acc2[t][c], 0, 0, 0);
    }
  }

  // ---- cosine: row pairs (2e,2e+1) live in same lane, regs (2i,2i+1) ----
  float p[2][2], qq[2][2], rr[2][2];
#pragma unroll
  for (int t = 0; t < 2; t++)
#pragma unroll
    for (int i = 0; i < 2; i++) { p[t][i] = 0.f; qq[t][i] = 0.f; rr[t][i] = 0.f; }
#pragma unroll
  for (int c = 0; c < 8; c++)
#pragma unroll
    for (int t = 0; t < 2; t++)
#pragma unroll
      for (int i = 0; i < 2; i++) {
        float hx = acc2[t][c][2 * i]     + b2j[c];
        float hy = acc2[t][c][2 * i + 1] + b2j[c];
        p[t][i]  += hx * hy;
        qq[t][i] += hx * hx;
        rr[t][i] += hy * hy;
      }
#pragma unroll
  for (int m = 1; m < 16; m <<= 1)
#pragma unroll
    for (int t = 0; t < 2; t++)
#pragma unroll
      for (int i = 0; i < 2; i++) {
        p[t][i]  += __shfl_xor(p[t][i], m, 64);
        qq[t][i] += __shfl_xor(qq[t][i], m, 64);
        rr[t][i] += __shfl_xor(rr[t][i], m, 64);
      }
  if (l15 == 0) {
#pragma unroll
    for (int t = 0; t < 2; t++)
#pragma unroll
      for (int i = 0; i < 2; i++) {
        int row = rowbase + t * 16 + quad * 4 + 2 * i;
        int e = row >> 1;
        float n1 = fmaxf(sqrtf(qq[t][i]), 1e-8f);
        float n2 = fmaxf(sqrtf(rr[t][i]), 1e-8f);
        float w = (p[t][i] / (n1 * n2) + 1.f) * 0.5f;
        ew_out[e] = w;
        ew_ws[e] = w;
        atomicAdd(deg + eidx[e], w);
        atomicAdd(cnt + eidx[EE + e], 1);
      }
  }
}

// ---------------- degree -> D^-1/2 ----------------
__global__ void dis_kernel(const float* __restrict__ deg, float* __restrict__ dis) {
  int i = blockIdx.x * 256 + threadIdx.x;
  if (i < NN) {
    float d = deg[i];
    dis[i] = d > 0.f ? 1.f / sqrtf(fmaxf(d, 1e-30f)) : 0.f;
  }
}

// ---------------- exclusive scan of in-degree counts ----------------
__global__ __launch_bounds__(1024) void scan_kernel(const int* __restrict__ cnt, int* __restrict__ ptr) {
  __shared__ int sums[1024];
  int tid = threadIdx.x;
  const int n = NN;
  const int chunk = (n + 1023) / 1024;
  int base = tid * chunk;
  int s = 0;
  for (int i = 0; i < chunk; i++) { int idx = base + i; if (idx < n) s += cnt[idx]; }
  sums[tid] = s;
  __syncthreads();
  for (int off = 1; off < 1024; off <<= 1) {
    int v = (tid >= off) ? sums[tid - off] : 0;
    __syncthreads();
    sums[tid] += v;
    __syncthreads();
  }
  int run = (tid == 0) ? 0 : sums[tid - 1];
  for (int i = 0; i < chunk; i++) {
    int idx = base + i;
    if (idx < n) { ptr[idx] = run; run += cnt[idx]; }
  }
  if (tid == 1023) ptr[n] = run;
}

// ---------------- CSR fill (by destination col), value = -dis[row]*ew*dis[col] ----------------
__global__ void fill_kernel(const int* __restrict__ eidx, const float* __restrict__ ew,
                            const float* __restrict__ dis, const int* __restrict__ ptr,
                            int* __restrict__ fill, int* __restrict__ cidx, float* __restrict__ cval) {
  int e = blockIdx.x * 256 + threadIdx.x;
  if (e < EE) {
    int r = eidx[e], c = eidx[EE + e];
    float nv = -dis[r] * ew[e] * dis[c];
    int pos = ptr[c] + atomicAdd(&fill[c], 1);
    cidx[pos] = r;
    cval[pos] = nv;
  }
}

// ---------------- sparse prop: y[c] = alpha * sum_e val*x[row]  (- sub[c]) ----------------
__global__ __launch_bounds__(256) void prop_kernel(
    const float* __restrict__ x, int ldx,
    const int* __restrict__ cidx, const float* __restrict__ cval,
    const int* __restrict__ ptr,
    float* __restrict__ y, int ldy,
    float alpha, const float* __restrict__ sub, int ldsub)
{
  int c = blockIdx.x * 4 + (threadIdx.x >> 6);
  if (c >= NN) return;
  int lane = threadIdx.x & 63;
  int d = lane * 4;
  int p0 = ptr[c], p1 = ptr[c + 1];
  float ax = 0.f, ay = 0.f, az = 0.f, aw = 0.f;
  int p = p0;
  for (; p + 1 < p1; p += 2) {
    int r0 = cidx[p], r1 = cidx[p + 1];
    float w0 = cval[p], w1v = cval[p + 1];
    float4 v0 = *(const float4*)(x + (size_t)r0 * ldx + d);
    float4 v1 = *(const float4*)(x + (size_t)r1 * ldx + d);
    ax += w0 * v0.x + w1v * v1.x;
    ay += w0 * v0.y + w1v * v1.y;
    az += w0 * v0.z + w1v * v1.z;
    aw += w0 * v0.w + w1v * v1.w;
  }
  if (p < p1) {
    int r0 = cidx[p]; float w0 = cval[p];
    float4 v0 = *(const float4*)(x + (size_t)r0 * ldx + d);
    ax += w0 * v0.x; ay += w0 * v0.y; az += w0 * v0.z; aw += w0 * v0.w;
  }
  float4 o;
  if (sub) {
    float4 s = *(const float4*)(sub + (size_t)c * ldsub + d);
    o.x = alpha * ax - s.x; o.y = alpha * ay - s.y;
    o.z = alpha * az - s.z; o.w = alpha * aw - s.w;
  } else {
    o.x = ax; o.y = ay; o.z = az; o.w = aw;
  }
  *(float4*)(y + (size_t)c * ldy + d) = o;
}

// ---------------- tiled fp32 GEMM: C = post( sum_c A_c @ B[c*256..] ) ----------------
__global__ __launch_bounds__(256) void gemm_kernel(
    const float* A0, const float* A1, const float* A2, const float* A3,
    int l0, int l1, int l2, int l3, int nchunks,
    const float* __restrict__ B,
    float* __restrict__ C, int ldc, int M,
    const float* __restrict__ bias, const float* __restrict__ bng, const float* __restrict__ bnb)
{
  __shared__ float As[16][68];
  __shared__ float Bs[16][64];
  int tid = threadIdx.x;
  int tx = tid & 15, ty = tid >> 4;
  int m0 = blockIdx.x * 64;
  int n0 = blockIdx.y * 64;
  float acc[4][4] = {};
  const float* Ap[4] = {A0, A1, A2, A3};
  int Al[4] = {l0, l1, l2, l3};
  int arow = tid >> 2;
  int akq = (tid & 3) * 4;
  int brow = tid >> 4;
  int bcol = (tid & 15) * 4;
  bool aval = (m0 + arow) < M;

  for (int c = 0; c < nchunks; c++) {
    const float* A = Ap[c];
    int lda = Al[c];
    const float* Arow = A + (size_t)(m0 + arow) * lda;
    for (int kb = 0; kb < 256; kb += 16) {
      float4 av = aval ? *(const float4*)(Arow + kb + akq) : make_float4(0.f, 0.f, 0.f, 0.f);
      float4 bv = *(const float4*)(B + (size_t)(c * 256 + kb + brow) * 256 + n0 + bcol);
      __syncthreads();
      As[akq + 0][arow] = av.x;
      As[akq + 1][arow] = av.y;
      As[akq + 2][arow] = av.z;
      As[akq + 3][arow] = av.w;
      *(float4*)&Bs[brow][bcol] = bv;
      __syncthreads();
#pragma unroll
      for (int k = 0; k < 16; k++) {
        float4 a4 = *(const float4*)&As[k][ty * 4];
        float4 b4 = *(const float4*)&Bs[k][tx * 4];
        float avv[4] = {a4.x, a4.y, a4.z, a4.w};
        float bvv[4] = {b4.x, b4.y, b4.z, b4.w};
#pragma unroll
        for (int i = 0; i < 4; i++)
#pragma unroll
          for (int jj = 0; jj < 4; jj++)
            acc[i][jj] += avv[i] * bvv[jj];
      }
    }
  }

#pragma unroll
  for (int i = 0; i < 4; i++) {
    int m = m0 + ty * 4 + i;
    if (m < M) {
#pragma unroll
      for (int jj = 0; jj < 4; jj++) {
        int n = n0 + tx * 4 + jj;
        float v = acc[i][jj];
        if (bias) v += bias[n];
        v = fmaxf(v, 0.f);
        if (bng) v = v * (bng[n] * RSBN) + bnb[n];
        C[(size_t)m * ldc + n] = v;
      }
    }
  }
}

// ---------------- final 256x2 matvec per node ----------------
__global__ __launch_bounds__(256) void logit_kernel(
    const float* __restrict__ z, const float* __restrict__ w2,
    const float* __restrict__ b2, float* __restrict__ out)
{
  int node = blockIdx.x * 4 + (threadIdx.x >> 6);
  if (node >= NN) return;
  int lane = threadIdx.x & 63;
  int k = lane * 4;
  float4 zv = *(const float4*)(z + (size_t)node * 256 + k);
  float4 wa = *(const float4*)(w2 + k * 2);
  float4 wb = *(const float4*)(w2 + k * 2 + 4);
  float a0 = zv.x * wa.x + zv.y * wa.z + zv.z * wb.x + zv.w * wb.z;
  float a1 = zv.x * wa.y + zv.y * wa.w + zv.z * wb.y + zv.w * wb.w;
#pragma unroll
  for (int m = 32; m >= 1; m >>= 1) {
    a0 += __shfl_xor(a0, m, 64);
    a1 += __shfl_xor(a1, m, 64);
  }
  if (lane == 0) {
    out[(size_t)node * 2]     = a0 + b2[0];
    out[(size_t)node * 2 + 1] = a1 + b2[1];
  }
}

extern "C" void kernel_launch(void* const* d_in, const int* in_sizes, int n_in,
                              void* d_out, int out_size, void* d_ws, size_t ws_size,
                              hipStream_t stream) {
  const float* features = (const float*)d_in[0];
  const int*   eidx     = (const int*)d_in[1];
  const float* xin      = (const float*)d_in[2];
  const float* cheb_w   = (const float*)d_in[3];
  const float* en_w1    = (const float*)d_in[4];
  const float* en_b1    = (const float*)d_in[5];
  const float* en_g1    = (const float*)d_in[6];
  const float* en_be1   = (const float*)d_in[7];
  const float* en_w2    = (const float*)d_in[8];
  const float* en_b2    = (const float*)d_in[9];
  const float* cls_w1   = (const float*)d_in[10];
  const float* cls_b1   = (const float*)d_in[11];
  const float* cls_g    = (const float*)d_in[12];
  const float* cls_b    = (const float*)d_in[13];
  const float* cls_w2   = (const float*)d_in[14];
  const float* cls_b2   = (const float*)d_in[15];
  float* out = (float*)d_out;

  char* ws = (char*)d_ws;
  size_t off = 0;
  auto alloc = [&](size_t bytes) -> void* {
    void* p = ws + off;
    off += (bytes + 255) & ~(size_t)255;
    return p;
  };
  float* deg  = (float*)alloc((size_t)NN * 4);
  int*   cnt  = (int*)  alloc((size_t)NN * 4);
  int*   fil  = (int*)  alloc((size_t)NN * 4);
  size_t zero_len = off;                       // deg+cnt+fil zeroed in one memset
  float* dis  = (float*)alloc((size_t)NN * 4);
  int*   ptr  = (int*)  alloc((size_t)(NN + 1) * 4);
  float* ew   = (float*)alloc((size_t)EE * 4);
  int*   cidx = (int*)  alloc((size_t)EE * 4);
  float* cval = (float*)alloc((size_t)EE * 4);
  float* Tx1  = (float*)alloc((size_t)NN * 256 * 4);
  float* Tx2  = (float*)alloc((size_t)NN * 256 * 4);
  float* zbuf = (float*)alloc((size_t)NN * 256 * 4);
  float* jk   = (float*)alloc((size_t)NN * 1024 * 4);

  hipMemsetAsync(deg, 0, zero_len, stream);

  // edge weights + degree + in-degree counts (2E/128 = 6250 blocks)
  edge_kernel<<<6250, 256, 0, stream>>>(xin, eidx, en_w1, en_b1, en_g1, en_be1,
                                        en_w2, en_b2, out + (size_t)NN * 2, ew, deg, cnt);
  dis_kernel<<<(NN + 255) / 256, 256, 0, stream>>>(deg, dis);
  scan_kernel<<<1, 1024, 0, stream>>>(cnt, ptr);
  fill_kernel<<<(EE + 255) / 256, 256, 0, stream>>>(eidx, ew, dis, ptr, fil, cidx, cval);

  dim3 ggrid(313, 4);
  for (int i = 0; i < 4; i++) {
    const float* x = (i == 0) ? features : (jk + (size_t)(i - 1) * 256);
    int ldx = (i == 0) ? 256 : 1024;
    prop_kernel<<<NN / 4, 256, 0, stream>>>(x, ldx, cidx, cval, ptr, Tx1, 256, 1.f, nullptr, 0);
    prop_kernel<<<NN / 4, 256, 0, stream>>>(Tx1, 256, cidx, cval, ptr, Tx2, 256, 2.f, x, ldx);
    gemm_kernel<<<ggrid, 256, 0, stream>>>(x, Tx1, Tx2, nullptr, ldx, 256, 256, 0, 3,
                                           cheb_w + (size_t)i * 3 * 256 * 256,
                                           jk + (size_t)i * 256, 1024, NN,
                                           nullptr, nullptr, nullptr);
  }

  // cls head: z = BN(relu(jk @ W1 + b1)), logit = z @ W2 + b2
  gemm_kernel<<<ggrid, 256, 0, stream>>>(jk, jk + 256, jk + 512, jk + 768,
                                         1024, 1024, 1024, 1024, 4,
                                         cls_w1, zbuf, 256, NN,
                                         cls_b1, cls_g, cls_b);
  logit_kernel<<<NN / 4, 256, 0, stream>>>(zbuf, cls_w2, cls_b2, out);
}

// Round 3
// 745.660 us; speedup vs baseline: 4.2432x; 1.7839x over previous
//
#include <hip/hip_runtime.h>

#define NN 20000
#define EE 400000
#define RSBN 0.9999950000374997f   // 1/sqrt(1+1e-5)

typedef __attribute__((ext_vector_type(8))) short short8;
typedef __attribute__((ext_vector_type(8))) unsigned short ushort8;
typedef __attribute__((ext_vector_type(4))) float floatx4;

__device__ __forceinline__ short f2bf(float f) {
  union { float f; unsigned u; } v; v.f = f;
  unsigned r = v.u + 0x7fffu + ((v.u >> 16) & 1u);   // RNE
  return (short)(r >> 16);
}
__device__ __forceinline__ float bf2f(unsigned short u) {
  union { unsigned u; float f; } v; v.u = ((unsigned)u) << 16;
  return v.f;
}
__device__ __forceinline__ void gl_lds16(const void* g, void* l) {
  __builtin_amdgcn_global_load_lds(
      (const __attribute__((address_space(1))) unsigned*)g,
      (__attribute__((address_space(3))) unsigned*)l, 16, 0, 0);
}

// ---------------- edge parser + edge weight (bf16 MFMA) ----------------
#define ASP 136
__global__ __launch_bounds__(256, 2) void edge_kernel(
    const float* __restrict__ xin, const int* __restrict__ eidx,
    const float* __restrict__ w1, const float* __restrict__ b1,
    const float* __restrict__ g1, const float* __restrict__ be1,
    const float* __restrict__ w2, const float* __restrict__ b2,
    float* __restrict__ ew_out, float* __restrict__ ew_ws,
    float* __restrict__ deg, int* __restrict__ cnt)
{
  __shared__ short w1f[8 * 64 * 8];
  __shared__ short w2f[4 * 8 * 64 * 8];
  __shared__ short as_s[128 * ASP];

  int tid = threadIdx.x;
  int lane = tid & 63;
  int wv = tid >> 6;
  int l15 = lane & 15;
  int quad = lane >> 4;

#pragma unroll
  for (int i = 0; i < 16; i++) {
    int idx = i * 256 + tid;
    int k = idx >> 7, n = idx & 127;
    int pos = ((n >> 4) * 64 + (k >> 3) * 16 + (n & 15)) * 8 + (k & 7);
    w1f[pos] = f2bf(w1[idx]);
  }
#pragma unroll
  for (int i = 0; i < 64; i++) {
    int idx = i * 256 + tid;
    int k = idx >> 7, n = idx & 127;
    int pos = (((k >> 5) * 8 + (n >> 4)) * 64 + ((k >> 3) & 3) * 16 + (n & 15)) * 8 + (k & 7);
    w2f[pos] = f2bf(w2[idx]);
  }

  float b1j[8], s1j[8], be1j[8], b2j[8];
#pragma unroll
  for (int c = 0; c < 8; c++) {
    int n = c * 16 + l15;
    b1j[c] = b1[n]; s1j[c] = g1[n] * RSBN; be1j[c] = be1[n]; b2j[c] = b2[n];
  }

  int rowbase = blockIdx.x * 128 + wv * 32;

  short8 af[2];
#pragma unroll
  for (int t = 0; t < 2; t++) {
    const float* xp = xin + (size_t)(rowbase + t * 16 + l15) * 32 + quad * 8;
    float4 v0 = *(const float4*)xp;
    float4 v1 = *(const float4*)(xp + 4);
    short8 a;
    a[0] = f2bf(v0.x); a[1] = f2bf(v0.y); a[2] = f2bf(v0.z); a[3] = f2bf(v0.w);
    a[4] = f2bf(v1.x); a[5] = f2bf(v1.y); a[6] = f2bf(v1.z); a[7] = f2bf(v1.w);
    af[t] = a;
  }

  __syncthreads();

  floatx4 acc[2][8];
#pragma unroll
  for (int t = 0; t < 2; t++)
#pragma unroll
    for (int c = 0; c < 8; c++) {
      floatx4 z = {0.f, 0.f, 0.f, 0.f};
      acc[t][c] = __builtin_amdgcn_mfma_f32_16x16x32_bf16(
          af[t], *(const short8*)&w1f[(c * 64 + lane) * 8], z, 0, 0, 0);
    }

#pragma unroll
  for (int t = 0; t < 2; t++)
#pragma unroll
    for (int c = 0; c < 8; c++)
#pragma unroll
      for (int r = 0; r < 4; r++) {
        float a = fmaxf(acc[t][c][r] + b1j[c], 0.f) * s1j[c] + be1j[c];
        as_s[(wv * 32 + t * 16 + quad * 4 + r) * ASP + c * 16 + l15] = f2bf(a);
      }

  floatx4 acc2[2][8];
#pragma unroll
  for (int t = 0; t < 2; t++)
#pragma unroll
    for (int c = 0; c < 8; c++) acc2[t][c] = (floatx4){0.f, 0.f, 0.f, 0.f};
#pragma unroll
  for (int s = 0; s < 4; s++) {
    short8 a2[2];
#pragma unroll
    for (int t = 0; t < 2; t++)
      a2[t] = *(const short8*)&as_s[(wv * 32 + t * 16 + l15) * ASP + s * 32 + quad * 8];
#pragma unroll
    for (int c = 0; c < 8; c++) {
      short8 bf = *(const short8*)&w2f[((s * 8 + c) * 64 + lane) * 8];
#pragma unroll
      for (int t = 0; t < 2; t++)
        acc2[t][c] = __builtin_amdgcn_mfma_f32_16x16x32_bf16(a2[t], bf, acc2[t][c], 0, 0, 0);
    }
  }

  float p[2][2], qq[2][2], rr[2][2];
#pragma unroll
  for (int t = 0; t < 2; t++)
#pragma unroll
    for (int i = 0; i < 2; i++) { p[t][i] = 0.f; qq[t][i] = 0.f; rr[t][i] = 0.f; }
#pragma unroll
  for (int c = 0; c < 8; c++)
#pragma unroll
    for (int t = 0; t < 2; t++)
#pragma unroll
      for (int i = 0; i < 2; i++) {
        float hx = acc2[t][c][2 * i]     + b2j[c];
        float hy = acc2[t][c][2 * i + 1] + b2j[c];
        p[t][i]  += hx * hy;
        qq[t][i] += hx * hx;
        rr[t][i] += hy * hy;
      }
#pragma unroll
  for (int m = 1; m < 16; m <<= 1)
#pragma unroll
    for (int t = 0; t < 2; t++)
#pragma unroll
      for (int i = 0; i < 2; i++) {
        p[t][i]  += __shfl_xor(p[t][i], m, 64);
        qq[t][i] += __shfl_xor(qq[t][i], m, 64);
        rr[t][i] += __shfl_xor(rr[t][i], m, 64);
      }
  if (l15 == 0) {
#pragma unroll
    for (int t = 0; t < 2; t++)
#pragma unroll
      for (int i = 0; i < 2; i++) {
        int row = rowbase + t * 16 + quad * 4 + 2 * i;
        int e = row >> 1;
        float n1 = fmaxf(sqrtf(qq[t][i]), 1e-8f);
        float n2 = fmaxf(sqrtf(rr[t][i]), 1e-8f);
        float w = (p[t][i] / (n1 * n2) + 1.f) * 0.5f;
        ew_out[e] = w;
        ew_ws[e] = w;
        atomicAdd(deg + eidx[e], w);
        atomicAdd(cnt + eidx[EE + e], 1);
      }
  }
}

// ---------------- features fp32 -> bf16 ----------------
__global__ __launch_bounds__(256) void fconv_kernel(const float* __restrict__ src,
                                                    unsigned short* __restrict__ dst) {
  size_t i = ((size_t)blockIdx.x * 256 + threadIdx.x) * 8;
  float4 a = *(const float4*)(src + i);
  float4 b = *(const float4*)(src + i + 4);
  ushort8 o;
  o[0] = f2bf(a.x); o[1] = f2bf(a.y); o[2] = f2bf(a.z); o[3] = f2bf(a.w);
  o[4] = f2bf(b.x); o[5] = f2bf(b.y); o[6] = f2bf(b.z); o[7] = f2bf(b.w);
  *(ushort8*)(dst + i) = o;
}

// ---------------- weights: transpose 256x256 chunks, fp32 -> bf16 ----------------
// z<12: cheb chunk z=(l*3+c) -> wtc + l*196608 + c*256, ldk=768
// z>=12: cls_w1 chunk c=z-12 -> clsT + c*256, ldk=1024
__global__ __launch_bounds__(256) void wconv_kernel(
    const float* __restrict__ cheb_w, const float* __restrict__ cls_w1,
    unsigned short* __restrict__ wtc, unsigned short* __restrict__ clsT)
{
  __shared__ unsigned short tile[64][80];
  int z = blockIdx.z;
  const float* src; unsigned short* dst; int ldk;
  if (z < 12) {
    int l = z / 3, c = z % 3;
    src = cheb_w + (size_t)z * 65536;
    dst = wtc + (size_t)l * 196608 + c * 256;
    ldk = 768;
  } else {
    int c = z - 12;
    src = cls_w1 + (size_t)c * 65536;
    dst = clsT + c * 256;
    ldk = 1024;
  }
  int t = threadIdx.x;
  int k0 = blockIdx.x * 64, n0 = blockIdx.y * 64;
#pragma unroll
  for (int pass = 0; pass < 4; pass++) {
    int kk = pass * 16 + (t >> 4);
    int nl = (t & 15) * 4;
    float4 v = *(const float4*)(src + (size_t)(k0 + kk) * 256 + n0 + nl);
    tile[nl + 0][kk] = f2bf(v.x);
    tile[nl + 1][kk] = f2bf(v.y);
    tile[nl + 2][kk] = f2bf(v.z);
    tile[nl + 3][kk] = f2bf(v.w);
  }
  __syncthreads();
  int nl = t >> 2, kc = (t & 3) * 16;
  ushort8 v0 = *(const ushort8*)&tile[nl][kc];
  ushort8 v1 = *(const ushort8*)&tile[nl][kc + 8];
  unsigned short* dp = dst + (size_t)(n0 + nl) * ldk + k0 + kc;
  *(ushort8*)dp = v0;
  *(ushort8*)(dp + 8) = v1;
}

// ---------------- degree -> D^-1/2 ----------------
__global__ void dis_kernel(const float* __restrict__ deg, float* __restrict__ dis) {
  int i = blockIdx.x * 256 + threadIdx.x;
  if (i < NN) {
    float d = deg[i];
    dis[i] = d > 0.f ? 1.f / sqrtf(fmaxf(d, 1e-30f)) : 0.f;
  }
}

// ---------------- exclusive scan of in-degree counts ----------------
__global__ __launch_bounds__(1024) void scan_kernel(const int* __restrict__ cnt, int* __restrict__ ptr) {
  __shared__ int sums[1024];
  int tid = threadIdx.x;
  const int n = NN;
  const int chunk = (n + 1023) / 1024;
  int base = tid * chunk;
  int s = 0;
  for (int i = 0; i < chunk; i++) { int idx = base + i; if (idx < n) s += cnt[idx]; }
  sums[tid] = s;
  __syncthreads();
  for (int off = 1; off < 1024; off <<= 1) {
    int v = (tid >= off) ? sums[tid - off] : 0;
    __syncthreads();
    sums[tid] += v;
    __syncthreads();
  }
  int run = (tid == 0) ? 0 : sums[tid - 1];
  for (int i = 0; i < chunk; i++) {
    int idx = base + i;
    if (idx < n) { ptr[idx] = run; run += cnt[idx]; }
  }
  if (tid == 1023) ptr[n] = run;
}

// ---------------- CSR fill ----------------
__global__ void fill_kernel(const int* __restrict__ eidx, const float* __restrict__ ew,
                            const float* __restrict__ dis, const int* __restrict__ ptr,
                            int* __restrict__ fill, int* __restrict__ cidx, float* __restrict__ cval) {
  int e = blockIdx.x * 256 + threadIdx.x;
  if (e < EE) {
    int r = eidx[e], c = eidx[EE + e];
    float nv = -dis[r] * ew[e] * dis[c];
    int pos = ptr[c] + atomicAdd(&fill[c], 1);
    cidx[pos] = r;
    cval[pos] = nv;
  }
}

// ---------------- sparse prop (bf16 x/y): y[c] = alpha*sum val*x[row] (- sub[c]) ----------------
// half-wave (32 lanes) per node, lane covers 8 columns (16B)
__global__ __launch_bounds__(256) void prop_kernel(
    const unsigned short* __restrict__ x, int ldx,
    const int* __restrict__ cidx, const float* __restrict__ cval,
    const int* __restrict__ ptr,
    unsigned short* __restrict__ y, int ldy,
    float alpha, const unsigned short* __restrict__ sub, int ldsub)
{
  int c = blockIdx.x * 8 + (threadIdx.x >> 5);
  int lane5 = threadIdx.x & 31;
  int d = lane5 * 8;
  int p0 = ptr[c], p1 = ptr[c + 1];
  float a[8] = {0.f, 0.f, 0.f, 0.f, 0.f, 0.f, 0.f, 0.f};
  int p = p0;
  for (; p + 1 < p1; p += 2) {
    int r0 = cidx[p], r1 = cidx[p + 1];
    float w0 = cval[p], w1v = cval[p + 1];
    ushort8 v0 = *(const ushort8*)(x + (size_t)r0 * ldx + d);
    ushort8 v1 = *(const ushort8*)(x + (size_t)r1 * ldx + d);
#pragma unroll
    for (int j = 0; j < 8; j++) a[j] += w0 * bf2f(v0[j]) + w1v * bf2f(v1[j]);
  }
  if (p < p1) {
    int r0 = cidx[p]; float w0 = cval[p];
    ushort8 v0 = *(const ushort8*)(x + (size_t)r0 * ldx + d);
#pragma unroll
    for (int j = 0; j < 8; j++) a[j] += w0 * bf2f(v0[j]);
  }
  ushort8 o;
  if (sub) {
    ushort8 sv = *(const ushort8*)(sub + (size_t)c * ldsub + d);
#pragma unroll
    for (int j = 0; j < 8; j++) o[j] = f2bf(alpha * a[j] - bf2f(sv[j]));
  } else {
#pragma unroll
    for (int j = 0; j < 8; j++) o[j] = f2bf(a[j]);
  }
  *(ushort8*)(y + (size_t)c * ldy + d) = o;
}

// ---------------- bf16 MFMA GEMM: C = post( sum_c A_c @ B_c ) ----------------
// Tile 64(M) x 128(N), BK=32, 4 waves 2x2. BT is pre-transposed [N][K] bf16.
// Cb: bf16 out (relu). Cf: fp32 out (bias+relu+BN).
__global__ __launch_bounds__(256, 2) void mgemm_kernel(
    const unsigned short* A0, const unsigned short* A1,
    const unsigned short* A2, const unsigned short* A3,
    int l0, int l1, int l2, int l3, int nchunks,
    const unsigned short* __restrict__ BT, int ldbt,
    unsigned short* __restrict__ Cb, float* __restrict__ Cf, int ldc, int M,
    const float* __restrict__ bias, const float* __restrict__ bng,
    const float* __restrict__ bnb)
{
  __shared__ short As[4 * 64 * 8];     // [kchunk][row][8]
  __shared__ short Bs[4 * 128 * 8];    // [kchunk][col][8]
  int tid = threadIdx.x;
  int lane = tid & 63;
  int wv = tid >> 6;
  int l15 = lane & 15, quad = lane >> 4;
  int wr = wv >> 1, wc = wv & 1;
  int m0 = blockIdx.x * 64, n0 = blockIdx.y * 128;

  const unsigned short* Ap[4] = {A0, A1, A2, A3};
  int Al[4] = {l0, l1, l2, l3};

  int arow = tid & 63, ac = tid >> 6;
  int brow = tid & 127, bc = tid >> 7;

  floatx4 acc[2][4];
#pragma unroll
  for (int mi = 0; mi < 2; mi++)
#pragma unroll
    for (int nj = 0; nj < 4; nj++) acc[mi][nj] = (floatx4){0.f, 0.f, 0.f, 0.f};

  for (int c = 0; c < nchunks; c++) {
    const unsigned short* Abase = Ap[c] + (size_t)(m0 + arow) * Al[c] + ac * 8;
    const unsigned short* Bbase = BT + (size_t)(n0 + brow) * ldbt + c * 256 + bc * 8;
#pragma unroll 1
    for (int kb = 0; kb < 256; kb += 32) {
      __syncthreads();
      gl_lds16(Abase + kb, &As[tid * 8]);
      gl_lds16(Bbase + kb, &Bs[tid * 8]);
      gl_lds16(Bbase + 16 + kb, &Bs[(tid + 256) * 8]);
      __syncthreads();
      short8 af[2], bfv[4];
#pragma unroll
      for (int mi = 0; mi < 2; mi++)
        af[mi] = *(const short8*)&As[(quad * 64 + wr * 32 + mi * 16 + l15) * 8];
#pragma unroll
      for (int nj = 0; nj < 4; nj++)
        bfv[nj] = *(const short8*)&Bs[(quad * 128 + wc * 64 + nj * 16 + l15) * 8];
#pragma unroll
      for (int nj = 0; nj < 4; nj++)
#pragma unroll
        for (int mi = 0; mi < 2; mi++)
          acc[mi][nj] = __builtin_amdgcn_mfma_f32_16x16x32_bf16(af[mi], bfv[nj], acc[mi][nj], 0, 0, 0);
    }
  }

  if (Cb) {
#pragma unroll
    for (int mi = 0; mi < 2; mi++)
#pragma unroll
      for (int r = 0; r < 4; r++) {
        int row = m0 + wr * 32 + mi * 16 + quad * 4 + r;
        if (row < M) {
#pragma unroll
          for (int nj = 0; nj < 4; nj++) {
            int col = n0 + wc * 64 + nj * 16 + l15;
            Cb[(size_t)row * ldc + col] = (unsigned short)f2bf(fmaxf(acc[mi][nj][r], 0.f));
          }
        }
      }
  } else {
    float bs[4], g[4], bb[4];
#pragma unroll
    for (int nj = 0; nj < 4; nj++) {
      int col = n0 + wc * 64 + nj * 16 + l15;
      bs[nj] = bias[col]; g[nj] = bng[col] * RSBN; bb[nj] = bnb[col];
    }
#pragma unroll
    for (int mi = 0; mi < 2; mi++)
#pragma unroll
      for (int r = 0; r < 4; r++) {
        int row = m0 + wr * 32 + mi * 16 + quad * 4 + r;
        if (row < M) {
#pragma unroll
          for (int nj = 0; nj < 4; nj++) {
            int col = n0 + wc * 64 + nj * 16 + l15;
            float v = fmaxf(acc[mi][nj][r] + bs[nj], 0.f) * g[nj] + bb[nj];
            Cf[(size_t)row * ldc + col] = v;
          }
        }
      }
  }
}

// ---------------- final 256x2 matvec per node ----------------
__global__ __launch_bounds__(256) void logit_kernel(
    const float* __restrict__ z, const float* __restrict__ w2,
    const float* __restrict__ b2, float* __restrict__ out)
{
  int node = blockIdx.x * 4 + (threadIdx.x >> 6);
  if (node >= NN) return;
  int lane = threadIdx.x & 63;
  int k = lane * 4;
  float4 zv = *(const float4*)(z + (size_t)node * 256 + k);
  float4 wa = *(const float4*)(w2 + k * 2);
  float4 wb = *(const float4*)(w2 + k * 2 + 4);
  float a0 = zv.x * wa.x + zv.y * wa.z + zv.z * wb.x + zv.w * wb.z;
  float a1 = zv.x * wa.y + zv.y * wa.w + zv.z * wb.y + zv.w * wb.w;
#pragma unroll
  for (int m = 32; m >= 1; m >>= 1) {
    a0 += __shfl_xor(a0, m, 64);
    a1 += __shfl_xor(a1, m, 64);
  }
  if (lane == 0) {
    out[(size_t)node * 2]     = a0 + b2[0];
    out[(size_t)node * 2 + 1] = a1 + b2[1];
  }
}

extern "C" void kernel_launch(void* const* d_in, const int* in_sizes, int n_in,
                              void* d_out, int out_size, void* d_ws, size_t ws_size,
                              hipStream_t stream) {
  const float* features = (const float*)d_in[0];
  const int*   eidx     = (const int*)d_in[1];
  const float* xin      = (const float*)d_in[2];
  const float* cheb_w   = (const float*)d_in[3];
  const float* en_w1    = (const float*)d_in[4];
  const float* en_b1    = (const float*)d_in[5];
  const float* en_g1    = (const float*)d_in[6];
  const float* en_be1   = (const float*)d_in[7];
  const float* en_w2    = (const float*)d_in[8];
  const float* en_b2    = (const float*)d_in[9];
  const float* cls_w1   = (const float*)d_in[10];
  const float* cls_b1   = (const float*)d_in[11];
  const float* cls_g    = (const float*)d_in[12];
  const float* cls_b    = (const float*)d_in[13];
  const float* cls_w2   = (const float*)d_in[14];
  const float* cls_b2   = (const float*)d_in[15];
  float* out = (float*)d_out;

  char* ws = (char*)d_ws;
  size_t off = 0;
  auto alloc = [&](size_t bytes) -> void* {
    void* p = ws + off;
    off += (bytes + 255) & ~(size_t)255;
    return p;
  };
  float* deg  = (float*)alloc((size_t)NN * 4);
  int*   cnt  = (int*)  alloc((size_t)NN * 4);
  int*   fil  = (int*)  alloc((size_t)NN * 4);
  size_t zero_len = off;
  float* dis  = (float*)alloc((size_t)NN * 4);
  int*   ptr  = (int*)  alloc((size_t)(NN + 1) * 4);
  float* ew   = (float*)alloc((size_t)EE * 4);
  int*   cidx = (int*)  alloc((size_t)EE * 4);
  float* cval = (float*)alloc((size_t)EE * 4);
  unsigned short* featb = (unsigned short*)alloc((size_t)NN * 256 * 2);
  unsigned short* Tx1   = (unsigned short*)alloc((size_t)NN * 256 * 2);
  unsigned short* Tx2   = (unsigned short*)alloc((size_t)NN * 256 * 2);
  unsigned short* jk    = (unsigned short*)alloc((size_t)NN * 1024 * 2);
  float* zbuf = (float*)alloc((size_t)NN * 256 * 4);
  unsigned short* wtc   = (unsigned short*)alloc((size_t)4 * 196608 * 2);
  unsigned short* clsT  = (unsigned short*)alloc((size_t)256 * 1024 * 2);
  alloc(262144);   // overread pad for GEMM tail blocks

  hipMemsetAsync(deg, 0, zero_len, stream);

  edge_kernel<<<6250, 256, 0, stream>>>(xin, eidx, en_w1, en_b1, en_g1, en_be1,
                                        en_w2, en_b2, out + (size_t)NN * 2, ew, deg, cnt);
  fconv_kernel<<<2500, 256, 0, stream>>>(features, featb);
  wconv_kernel<<<dim3(4, 4, 16), 256, 0, stream>>>(cheb_w, cls_w1, wtc, clsT);
  dis_kernel<<<(NN + 255) / 256, 256, 0, stream>>>(deg, dis);
  scan_kernel<<<1, 1024, 0, stream>>>(cnt, ptr);
  fill_kernel<<<(EE + 255) / 256, 256, 0, stream>>>(eidx, ew, dis, ptr, fil, cidx, cval);

  dim3 ggrid(313, 2);
  for (int i = 0; i < 4; i++) {
    const unsigned short* x = (i == 0) ? featb : (jk + (size_t)(i - 1) * 256);
    int ldx = (i == 0) ? 256 : 1024;
    prop_kernel<<<2500, 256, 0, stream>>>(x, ldx, cidx, cval, ptr, Tx1, 256, 1.f, nullptr, 0);
    prop_kernel<<<2500, 256, 0, stream>>>(Tx1, 256, cidx, cval, ptr, Tx2, 256, 2.f, x, ldx);
    mgemm_kernel<<<ggrid, 256, 0, stream>>>(x, Tx1, Tx2, nullptr, ldx, 256, 256, 0, 3,
                                            wtc + (size_t)i * 196608, 768,
                                            jk + (size_t)i * 256, nullptr, 1024, NN,
                                            nullptr, nullptr, nullptr);
  }

  mgemm_kernel<<<ggrid, 256, 0, stream>>>(jk, jk + 256, jk + 512, jk + 768,
                                          1024, 1024, 1024, 1024, 4, clsT, 1024,
                                          nullptr, zbuf, 256, NN,
                                          cls_b1, cls_g, cls_b);
  logit_kernel<<<NN / 4, 256, 0, stream>>>(zbuf, cls_w2, cls_b2, out);
}

// Round 4
// 693.373 us; speedup vs baseline: 4.5632x; 1.0754x over previous
//
#include <hip/hip_runtime.h>

#define NN 20000
#define EE 400000
#define RSBN 0.9999950000374997f   // 1/sqrt(1+1e-5)

typedef __attribute__((ext_vector_type(8))) short short8;
typedef __attribute__((ext_vector_type(8))) unsigned short ushort8;
typedef __attribute__((ext_vector_type(4))) float floatx4;

__device__ __forceinline__ short f2bf(float f) {
  union { float f; unsigned u; } v; v.f = f;
  unsigned r = v.u + 0x7fffu + ((v.u >> 16) & 1u);   // RNE
  return (short)(r >> 16);
}
__device__ __forceinline__ float bf2f(unsigned short u) {
  union { unsigned u; float f; } v; v.u = ((unsigned)u) << 16;
  return v.f;
}
__device__ __forceinline__ void gl_lds16(const void* g, void* l) {
  __builtin_amdgcn_global_load_lds(
      (const __attribute__((address_space(1))) unsigned*)g,
      (__attribute__((address_space(3))) unsigned*)l, 16, 0, 0);
}

// ---------------- edge-parser weights -> fragment-layout bf16 (once) ----------------
// ewf[0..4096): W1 frags   ewf[4096..20480): W2 frags
__global__ __launch_bounds__(256) void ewconv_kernel(
    const float* __restrict__ w1, const float* __restrict__ w2,
    unsigned short* __restrict__ ewf)
{
  int tid = threadIdx.x;
#pragma unroll
  for (int i = 0; i < 16; i++) {
    int idx = i * 256 + tid;
    int k = idx >> 7, n = idx & 127;
    int pos = ((n >> 4) * 64 + (k >> 3) * 16 + (n & 15)) * 8 + (k & 7);
    ewf[pos] = f2bf(w1[idx]);
  }
#pragma unroll
  for (int i = 0; i < 64; i++) {
    int idx = i * 256 + tid;
    int k = idx >> 7, n = idx & 127;
    int pos = (((k >> 5) * 8 + (n >> 4)) * 64 + ((k >> 3) & 3) * 16 + (n & 15)) * 8 + (k & 7);
    ewf[4096 + pos] = f2bf(w2[idx]);
  }
}

// ---------------- edge parser + edge weight (bf16 MFMA) ----------------
// 512 threads = 8 waves, each wave 16 rows. Block: 128 rows x 128 cols.
#define ASP 136
__global__ __launch_bounds__(512, 4) void edge_kernel(
    const float* __restrict__ xin, const int* __restrict__ eidx,
    const unsigned short* __restrict__ ewf,
    const float* __restrict__ b1, const float* __restrict__ g1,
    const float* __restrict__ be1, const float* __restrict__ b2,
    float* __restrict__ ew_out, float* __restrict__ ew_ws,
    float* __restrict__ deg, int* __restrict__ cnt)
{
  __shared__ short wbuf[20480];       // [0..4096) w1f, [4096..20480) w2f
  __shared__ short as_s[128 * ASP];

  int tid = threadIdx.x;
  int lane = tid & 63;
  int wv = tid >> 6;                  // 0..7
  int l15 = lane & 15;
  int quad = lane >> 4;

  // stage weight fragments via DMA (no VALU, no conflicts)
#pragma unroll
  for (int i = 0; i < 5; i++)
    gl_lds16(ewf + (i * 512 + tid) * 8, &wbuf[(i * 512 + tid) * 8]);

  const short* w1f = wbuf;
  const short* w2f = wbuf + 4096;

  float b1j[8], s1j[8], be1j[8], b2j[8];
#pragma unroll
  for (int c = 0; c < 8; c++) {
    int n = c * 16 + l15;
    b1j[c] = b1[n]; s1j[c] = g1[n] * RSBN; be1j[c] = be1[n]; b2j[c] = b2[n];
  }

  int rowbase = blockIdx.x * 128 + wv * 16;

  // A fragment straight from global fp32
  short8 af;
  {
    const float* xp = xin + (size_t)(rowbase + l15) * 32 + quad * 8;
    float4 v0 = *(const float4*)xp;
    float4 v1 = *(const float4*)(xp + 4);
    af[0] = f2bf(v0.x); af[1] = f2bf(v0.y); af[2] = f2bf(v0.z); af[3] = f2bf(v0.w);
    af[4] = f2bf(v1.x); af[5] = f2bf(v1.y); af[6] = f2bf(v1.z); af[7] = f2bf(v1.w);
  }

  __syncthreads();   // weight fragments ready

  // GEMM1: K=32, 8 col-tiles
  floatx4 acc[8];
#pragma unroll
  for (int c = 0; c < 8; c++) {
    floatx4 z = {0.f, 0.f, 0.f, 0.f};
    acc[c] = __builtin_amdgcn_mfma_f32_16x16x32_bf16(
        af, *(const short8*)&w1f[(c * 64 + lane) * 8], z, 0, 0, 0);
  }

  // epilogue1: relu+BN -> bf16 activation tile (each wave touches only its 16 rows)
#pragma unroll
  for (int c = 0; c < 8; c++)
#pragma unroll
    for (int r = 0; r < 4; r++) {
      float a = fmaxf(acc[c][r] + b1j[c], 0.f) * s1j[c] + be1j[c];
      as_s[(wv * 16 + quad * 4 + r) * ASP + c * 16 + l15] = f2bf(a);
    }

  // GEMM2: K=128 in 4 steps
  floatx4 acc2[8];
#pragma unroll
  for (int c = 0; c < 8; c++) acc2[c] = (floatx4){0.f, 0.f, 0.f, 0.f};
#pragma unroll
  for (int s = 0; s < 4; s++) {
    short8 a2 = *(const short8*)&as_s[(wv * 16 + l15) * ASP + s * 32 + quad * 8];
#pragma unroll
    for (int c = 0; c < 8; c++) {
      short8 bf = *(const short8*)&w2f[((s * 8 + c) * 64 + lane) * 8];
      acc2[c] = __builtin_amdgcn_mfma_f32_16x16x32_bf16(a2, bf, acc2[c], 0, 0, 0);
    }
  }

  // cosine: row pairs (2e,2e+1) in same lane, regs (2i,2i+1)
  float p[2], qq[2], rr[2];
#pragma unroll
  for (int i = 0; i < 2; i++) { p[i] = 0.f; qq[i] = 0.f; rr[i] = 0.f; }
#pragma unroll
  for (int c = 0; c < 8; c++)
#pragma unroll
    for (int i = 0; i < 2; i++) {
      float hx = acc2[c][2 * i]     + b2j[c];
      float hy = acc2[c][2 * i + 1] + b2j[c];
      p[i]  += hx * hy;
      qq[i] += hx * hx;
      rr[i] += hy * hy;
    }
#pragma unroll
  for (int m = 1; m < 16; m <<= 1)
#pragma unroll
    for (int i = 0; i < 2; i++) {
      p[i]  += __shfl_xor(p[i], m, 64);
      qq[i] += __shfl_xor(qq[i], m, 64);
      rr[i] += __shfl_xor(rr[i], m, 64);
    }
  if (l15 == 0) {
#pragma unroll
    for (int i = 0; i < 2; i++) {
      int row = rowbase + quad * 4 + 2 * i;
      int e = row >> 1;
      float n1 = fmaxf(sqrtf(qq[i]), 1e-8f);
      float n2 = fmaxf(sqrtf(rr[i]), 1e-8f);
      float w = (p[i] / (n1 * n2) + 1.f) * 0.5f;
      ew_out[e] = w;
      ew_ws[e] = w;
      atomicAdd(deg + eidx[e], w);
      atomicAdd(cnt + eidx[EE + e], 1);
    }
  }
}

// ---------------- features fp32 -> bf16 ----------------
__global__ __launch_bounds__(256) void fconv_kernel(const float* __restrict__ src,
                                                    unsigned short* __restrict__ dst) {
  size_t i = ((size_t)blockIdx.x * 256 + threadIdx.x) * 8;
  float4 a = *(const float4*)(src + i);
  float4 b = *(const float4*)(src + i + 4);
  ushort8 o;
  o[0] = f2bf(a.x); o[1] = f2bf(a.y); o[2] = f2bf(a.z); o[3] = f2bf(a.w);
  o[4] = f2bf(b.x); o[5] = f2bf(b.y); o[6] = f2bf(b.z); o[7] = f2bf(b.w);
  *(ushort8*)(dst + i) = o;
}

// ---------------- weights: transpose 256x256 chunks, fp32 -> bf16 ----------------
__global__ __launch_bounds__(256) void wconv_kernel(
    const float* __restrict__ cheb_w, const float* __restrict__ cls_w1,
    unsigned short* __restrict__ wtc, unsigned short* __restrict__ clsT)
{
  __shared__ unsigned short tile[64][80];
  int z = blockIdx.z;
  const float* src; unsigned short* dst; int ldk;
  if (z < 12) {
    int l = z / 3, c = z % 3;
    src = cheb_w + (size_t)z * 65536;
    dst = wtc + (size_t)l * 196608 + c * 256;
    ldk = 768;
  } else {
    int c = z - 12;
    src = cls_w1 + (size_t)c * 65536;
    dst = clsT + c * 256;
    ldk = 1024;
  }
  int t = threadIdx.x;
  int k0 = blockIdx.x * 64, n0 = blockIdx.y * 64;
#pragma unroll
  for (int pass = 0; pass < 4; pass++) {
    int kk = pass * 16 + (t >> 4);
    int nl = (t & 15) * 4;
    float4 v = *(const float4*)(src + (size_t)(k0 + kk) * 256 + n0 + nl);
    tile[nl + 0][kk] = f2bf(v.x);
    tile[nl + 1][kk] = f2bf(v.y);
    tile[nl + 2][kk] = f2bf(v.z);
    tile[nl + 3][kk] = f2bf(v.w);
  }
  __syncthreads();
  int nl = t >> 2, kc = (t & 3) * 16;
  ushort8 v0 = *(const ushort8*)&tile[nl][kc];
  ushort8 v1 = *(const ushort8*)&tile[nl][kc + 8];
  unsigned short* dp = dst + (size_t)(n0 + nl) * ldk + k0 + kc;
  *(ushort8*)dp = v0;
  *(ushort8*)(dp + 8) = v1;
}

// ---------------- degree -> D^-1/2 ----------------
__global__ void dis_kernel(const float* __restrict__ deg, float* __restrict__ dis) {
  int i = blockIdx.x * 256 + threadIdx.x;
  if (i < NN) {
    float d = deg[i];
    dis[i] = d > 0.f ? 1.f / sqrtf(fmaxf(d, 1e-30f)) : 0.f;
  }
}

// ---------------- exclusive scan of in-degree counts ----------------
__global__ __launch_bounds__(1024) void scan_kernel(const int* __restrict__ cnt, int* __restrict__ ptr) {
  __shared__ int sums[1024];
  int tid = threadIdx.x;
  const int n = NN;
  const int chunk = (n + 1023) / 1024;
  int base = tid * chunk;
  int s = 0;
  for (int i = 0; i < chunk; i++) { int idx = base + i; if (idx < n) s += cnt[idx]; }
  sums[tid] = s;
  __syncthreads();
  for (int off = 1; off < 1024; off <<= 1) {
    int v = (tid >= off) ? sums[tid - off] : 0;
    __syncthreads();
    sums[tid] += v;
    __syncthreads();
  }
  int run = (tid == 0) ? 0 : sums[tid - 1];
  for (int i = 0; i < chunk; i++) {
    int idx = base + i;
    if (idx < n) { ptr[idx] = run; run += cnt[idx]; }
  }
  if (tid == 1023) ptr[n] = run;
}

// ---------------- CSR fill ----------------
__global__ void fill_kernel(const int* __restrict__ eidx, const float* __restrict__ ew,
                            const float* __restrict__ dis, const int* __restrict__ ptr,
                            int* __restrict__ fill, int* __restrict__ cidx, float* __restrict__ cval) {
  int e = blockIdx.x * 256 + threadIdx.x;
  if (e < EE) {
    int r = eidx[e], c = eidx[EE + e];
    float nv = -dis[r] * ew[e] * dis[c];
    int pos = ptr[c] + atomicAdd(&fill[c], 1);
    cidx[pos] = r;
    cval[pos] = nv;
  }
}

// ---------------- sparse prop (bf16): y[c] = alpha*sum val*x[row] (- sub[c]) ----------------
// half-wave (32 lanes) per node, lane covers 8 cols (16B), 4-edge unroll for MLP
__global__ __launch_bounds__(256) void prop_kernel(
    const unsigned short* __restrict__ x, int ldx,
    const int* __restrict__ cidx, const float* __restrict__ cval,
    const int* __restrict__ ptr,
    unsigned short* __restrict__ y, int ldy,
    float alpha, const unsigned short* __restrict__ sub, int ldsub)
{
  int c = blockIdx.x * 8 + (threadIdx.x >> 5);
  int lane5 = threadIdx.x & 31;
  int d = lane5 * 8;
  int p0 = ptr[c], p1 = ptr[c + 1];
  float a[8] = {0.f, 0.f, 0.f, 0.f, 0.f, 0.f, 0.f, 0.f};
  int p = p0;
  for (; p + 3 < p1; p += 4) {
    int r0 = cidx[p], r1 = cidx[p + 1], r2 = cidx[p + 2], r3 = cidx[p + 3];
    float w0 = cval[p], w1v = cval[p + 1], w2v = cval[p + 2], w3v = cval[p + 3];
    ushort8 v0 = *(const ushort8*)(x + (size_t)r0 * ldx + d);
    ushort8 v1 = *(const ushort8*)(x + (size_t)r1 * ldx + d);
    ushort8 v2 = *(const ushort8*)(x + (size_t)r2 * ldx + d);
    ushort8 v3 = *(const ushort8*)(x + (size_t)r3 * ldx + d);
#pragma unroll
    for (int j = 0; j < 8; j++)
      a[j] += w0 * bf2f(v0[j]) + w1v * bf2f(v1[j]) + w2v * bf2f(v2[j]) + w3v * bf2f(v3[j]);
  }
  for (; p < p1; p++) {
    int r0 = cidx[p]; float w0 = cval[p];
    ushort8 v0 = *(const ushort8*)(x + (size_t)r0 * ldx + d);
#pragma unroll
    for (int j = 0; j < 8; j++) a[j] += w0 * bf2f(v0[j]);
  }
  ushort8 o;
  if (sub) {
    ushort8 sv = *(const ushort8*)(sub + (size_t)c * ldsub + d);
#pragma unroll
    for (int j = 0; j < 8; j++) o[j] = f2bf(alpha * a[j] - bf2f(sv[j]));
  } else {
#pragma unroll
    for (int j = 0; j < 8; j++) o[j] = f2bf(a[j]);
  }
  *(ushort8*)(y + (size_t)c * ldy + d) = o;
}

// ---------------- bf16 MFMA GEMM: C = post( sum_c A_c @ B_c ) ----------------
__global__ __launch_bounds__(256, 2) void mgemm_kernel(
    const unsigned short* A0, const unsigned short* A1,
    const unsigned short* A2, const unsigned short* A3,
    int l0, int l1, int l2, int l3, int nchunks,
    const unsigned short* __restrict__ BT, int ldbt,
    unsigned short* __restrict__ Cb, float* __restrict__ Cf, int ldc, int M,
    const float* __restrict__ bias, const float* __restrict__ bng,
    const float* __restrict__ bnb)
{
  __shared__ short As[4 * 64 * 8];
  __shared__ short Bs[4 * 128 * 8];
  int tid = threadIdx.x;
  int lane = tid & 63;
  int wv = tid >> 6;
  int l15 = lane & 15, quad = lane >> 4;
  int wr = wv >> 1, wc = wv & 1;
  int m0 = blockIdx.x * 64, n0 = blockIdx.y * 128;

  const unsigned short* Ap[4] = {A0, A1, A2, A3};
  int Al[4] = {l0, l1, l2, l3};

  int arow = tid & 63, ac = tid >> 6;
  int brow = tid & 127, bc = tid >> 7;

  floatx4 acc[2][4];
#pragma unroll
  for (int mi = 0; mi < 2; mi++)
#pragma unroll
    for (int nj = 0; nj < 4; nj++) acc[mi][nj] = (floatx4){0.f, 0.f, 0.f, 0.f};

  for (int c = 0; c < nchunks; c++) {
    const unsigned short* Abase = Ap[c] + (size_t)(m0 + arow) * Al[c] + ac * 8;
    const unsigned short* Bbase = BT + (size_t)(n0 + brow) * ldbt + c * 256 + bc * 8;
#pragma unroll 1
    for (int kb = 0; kb < 256; kb += 32) {
      __syncthreads();
      gl_lds16(Abase + kb, &As[tid * 8]);
      gl_lds16(Bbase + kb, &Bs[tid * 8]);
      gl_lds16(Bbase + 16 + kb, &Bs[(tid + 256) * 8]);
      __syncthreads();
      short8 af[2], bfv[4];
#pragma unroll
      for (int mi = 0; mi < 2; mi++)
        af[mi] = *(const short8*)&As[(quad * 64 + wr * 32 + mi * 16 + l15) * 8];
#pragma unroll
      for (int nj = 0; nj < 4; nj++)
        bfv[nj] = *(const short8*)&Bs[(quad * 128 + wc * 64 + nj * 16 + l15) * 8];
#pragma unroll
      for (int nj = 0; nj < 4; nj++)
#pragma unroll
        for (int mi = 0; mi < 2; mi++)
          acc[mi][nj] = __builtin_amdgcn_mfma_f32_16x16x32_bf16(af[mi], bfv[nj], acc[mi][nj], 0, 0, 0);
    }
  }

  if (Cb) {
#pragma unroll
    for (int mi = 0; mi < 2; mi++)
#pragma unroll
      for (int r = 0; r < 4; r++) {
        int row = m0 + wr * 32 + mi * 16 + quad * 4 + r;
        if (row < M) {
#pragma unroll
          for (int nj = 0; nj < 4; nj++) {
            int col = n0 + wc * 64 + nj * 16 + l15;
            Cb[(size_t)row * ldc + col] = (unsigned short)f2bf(fmaxf(acc[mi][nj][r], 0.f));
          }
        }
      }
  } else {
    float bs[4], g[4], bb[4];
#pragma unroll
    for (int nj = 0; nj < 4; nj++) {
      int col = n0 + wc * 64 + nj * 16 + l15;
      bs[nj] = bias[col]; g[nj] = bng[col] * RSBN; bb[nj] = bnb[col];
    }
#pragma unroll
    for (int mi = 0; mi < 2; mi++)
#pragma unroll
      for (int r = 0; r < 4; r++) {
        int row = m0 + wr * 32 + mi * 16 + quad * 4 + r;
        if (row < M) {
#pragma unroll
          for (int nj = 0; nj < 4; nj++) {
            int col = n0 + wc * 64 + nj * 16 + l15;
            float v = fmaxf(acc[mi][nj][r] + bs[nj], 0.f) * g[nj] + bb[nj];
            Cf[(size_t)row * ldc + col] = v;
          }
        }
      }
  }
}

// ---------------- final 256x2 matvec per node ----------------
__global__ __launch_bounds__(256) void logit_kernel(
    const float* __restrict__ z, const float* __restrict__ w2,
    const float* __restrict__ b2, float* __restrict__ out)
{
  int node = blockIdx.x * 4 + (threadIdx.x >> 6);
  if (node >= NN) return;
  int lane = threadIdx.x & 63;
  int k = lane * 4;
  float4 zv = *(const float4*)(z + (size_t)node * 256 + k);
  float4 wa = *(const float4*)(w2 + k * 2);
  float4 wb = *(const float4*)(w2 + k * 2 + 4);
  float a0 = zv.x * wa.x + zv.y * wa.z + zv.z * wb.x + zv.w * wb.z;
  float a1 = zv.x * wa.y + zv.y * wa.w + zv.z * wb.y + zv.w * wb.w;
#pragma unroll
  for (int m = 32; m >= 1; m >>= 1) {
    a0 += __shfl_xor(a0, m, 64);
    a1 += __shfl_xor(a1, m, 64);
  }
  if (lane == 0) {
    out[(size_t)node * 2]     = a0 + b2[0];
    out[(size_t)node * 2 + 1] = a1 + b2[1];
  }
}

extern "C" void kernel_launch(void* const* d_in, const int* in_sizes, int n_in,
                              void* d_out, int out_size, void* d_ws, size_t ws_size,
                              hipStream_t stream) {
  const float* features = (const float*)d_in[0];
  const int*   eidx     = (const int*)d_in[1];
  const float* xin      = (const float*)d_in[2];
  const float* cheb_w   = (const float*)d_in[3];
  const float* en_w1    = (const float*)d_in[4];
  const float* en_b1    = (const float*)d_in[5];
  const float* en_g1    = (const float*)d_in[6];
  const float* en_be1   = (const float*)d_in[7];
  const float* en_w2    = (const float*)d_in[8];
  const float* en_b2    = (const float*)d_in[9];
  const float* cls_w1   = (const float*)d_in[10];
  const float* cls_b1   = (const float*)d_in[11];
  const float* cls_g    = (const float*)d_in[12];
  const float* cls_b    = (const float*)d_in[13];
  const float* cls_w2   = (const float*)d_in[14];
  const float* cls_b2   = (const float*)d_in[15];
  float* out = (float*)d_out;

  char* ws = (char*)d_ws;
  size_t off = 0;
  auto alloc = [&](size_t bytes) -> void* {
    void* p = ws + off;
    off += (bytes + 255) & ~(size_t)255;
    return p;
  };
  float* deg  = (float*)alloc((size_t)NN * 4);
  int*   cnt  = (int*)  alloc((size_t)NN * 4);
  int*   fil  = (int*)  alloc((size_t)NN * 4);
  size_t zero_len = off;
  float* dis  = (float*)alloc((size_t)NN * 4);
  int*   ptr  = (int*)  alloc((size_t)(NN + 1) * 4);
  float* ew   = (float*)alloc((size_t)EE * 4);
  int*   cidx = (int*)  alloc((size_t)EE * 4);
  float* cval = (float*)alloc((size_t)EE * 4);
  unsigned short* featb = (unsigned short*)alloc((size_t)NN * 256 * 2);
  unsigned short* Tx1   = (unsigned short*)alloc((size_t)NN * 256 * 2);
  unsigned short* Tx2   = (unsigned short*)alloc((size_t)NN * 256 * 2);
  unsigned short* jk    = (unsigned short*)alloc((size_t)NN * 1024 * 2);
  float* zbuf = (float*)alloc((size_t)NN * 256 * 4);
  unsigned short* wtc   = (unsigned short*)alloc((size_t)4 * 196608 * 2);
  unsigned short* clsT  = (unsigned short*)alloc((size_t)256 * 1024 * 2);
  unsigned short* ewf   = (unsigned short*)alloc((size_t)20480 * 2);
  alloc(262144);   // overread pad for GEMM tail blocks

  hipMemsetAsync(deg, 0, zero_len, stream);

  ewconv_kernel<<<1, 256, 0, stream>>>(en_w1, en_w2, ewf);
  edge_kernel<<<6250, 512, 0, stream>>>(xin, eidx, ewf, en_b1, en_g1, en_be1, en_b2,
                                        out + (size_t)NN * 2, ew, deg, cnt);
  fconv_kernel<<<2500, 256, 0, stream>>>(features, featb);
  wconv_kernel<<<dim3(4, 4, 16), 256, 0, stream>>>(cheb_w, cls_w1, wtc, clsT);
  dis_kernel<<<(NN + 255) / 256, 256, 0, stream>>>(deg, dis);
  scan_kernel<<<1, 1024, 0, stream>>>(cnt, ptr);
  fill_kernel<<<(EE + 255) / 256, 256, 0, stream>>>(eidx, ew, dis, ptr, fil, cidx, cval);

  dim3 ggrid(313, 2);
  for (int i = 0; i < 4; i++) {
    const unsigned short* x = (i == 0) ? featb : (jk + (size_t)(i - 1) * 256);
    int ldx = (i == 0) ? 256 : 1024;
    prop_kernel<<<2500, 256, 0, stream>>>(x, ldx, cidx, cval, ptr, Tx1, 256, 1.f, nullptr, 0);
    prop_kernel<<<2500, 256, 0, stream>>>(Tx1, 256, cidx, cval, ptr, Tx2, 256, 2.f, x, ldx);
    mgemm_kernel<<<ggrid, 256, 0, stream>>>(x, Tx1, Tx2, nullptr, ldx, 256, 256, 0, 3,
                                            wtc + (size_t)i * 196608, 768,
                                            jk + (size_t)i * 256, nullptr, 1024, NN,
                                            nullptr, nullptr, nullptr);
  }

  mgemm_kernel<<<ggrid, 256, 0, stream>>>(jk, jk + 256, jk + 512, jk + 768,
                                          1024, 1024, 1024, 1024, 4, clsT, 1024,
                                          nullptr, zbuf, 256, NN,
                                          cls_b1, cls_g, cls_b);
  logit_kernel<<<NN / 4, 256, 0, stream>>>(zbuf, cls_w2, cls_b2, out);
}

// Round 5
// 687.080 us; speedup vs baseline: 4.6050x; 1.0092x over previous
//
#include <hip/hip_runtime.h>
#include <hip/hip_bf16.h>

#define NN 20000
#define EE 400000
#define RSBN 0.9999950000374997f   // 1/sqrt(1+1e-5)

typedef __attribute__((ext_vector_type(8))) short short8;
typedef __attribute__((ext_vector_type(8))) unsigned short ushort8;
typedef __attribute__((ext_vector_type(4))) float floatx4;

__device__ __forceinline__ short f2bf(float f) {
  union { float f; unsigned u; } v; v.f = f;
  unsigned r = v.u + 0x7fffu + ((v.u >> 16) & 1u);   // RNE
  return (short)(r >> 16);
}
__device__ __forceinline__ unsigned f2bf2(float x, float y) {   // packed cvt
  union { __hip_bfloat162 h; unsigned u; } v;
  v.h = __float22bfloat162_rn(make_float2(x, y));
  return v.u;
}
__device__ __forceinline__ float bf2f(unsigned short u) {
  union { unsigned u; float f; } v; v.u = ((unsigned)u) << 16;
  return v.f;
}
__device__ __forceinline__ void gl_lds16(const void* g, void* l) {
  __builtin_amdgcn_global_load_lds(
      (const __attribute__((address_space(1))) unsigned*)g,
      (__attribute__((address_space(3))) unsigned*)l, 16, 0, 0);
}

// ---------------- edge-parser weights -> fragment-layout bf16 + folded consts ----------------
// shorts [0,4096): W1 frags | [4096,20480): W2' frags (BN-scaled)
// floats (as shorts) [20480,20736): b1[128] | [20736,20992): b2'[128]
__global__ __launch_bounds__(256) void ewconv_kernel(
    const float* __restrict__ w1, const float* __restrict__ w2,
    const float* __restrict__ g1, const float* __restrict__ be1,
    const float* __restrict__ b1, const float* __restrict__ b2,
    unsigned short* __restrict__ ewf)
{
  int tid = threadIdx.x;
#pragma unroll
  for (int i = 0; i < 16; i++) {
    int idx = i * 256 + tid;
    int k = idx >> 7, n = idx & 127;
    int pos = ((n >> 4) * 64 + (k >> 3) * 16 + (n & 15)) * 8 + (k & 7);
    ewf[pos] = f2bf(w1[idx]);
  }
#pragma unroll
  for (int i = 0; i < 64; i++) {
    int idx = i * 256 + tid;
    int k = idx >> 7, n = idx & 127;
    int pos = (((k >> 5) * 8 + (n >> 4)) * 64 + ((k >> 3) & 3) * 16 + (n & 15)) * 8 + (k & 7);
    ewf[4096 + pos] = f2bf(w2[idx] * g1[k] * RSBN);   // BN scale folded
  }
  float* fb = (float*)(ewf + 20480);
  if (tid < 128) {
    fb[tid] = b1[tid];
    float acc = b2[tid];
    for (int k = 0; k < 128; k++) acc += be1[k] * w2[k * 128 + tid] * g1[k] * RSBN;
    fb[128 + tid] = acc;
  }
}

// ---------------- edge parser + edge weight (bf16 MFMA) ----------------
// 512 threads = 8 waves, each wave 16 rows. Block: 128 rows x 128 cols.
#define ASP 136
__global__ __launch_bounds__(512, 4) void edge_kernel(
    const float* __restrict__ xin, const int* __restrict__ eidx,
    const unsigned short* __restrict__ ewf,
    float* __restrict__ ew_out,
    float* __restrict__ deg, int* __restrict__ cnt)
{
  __shared__ short wbuf[20992];       // frags + biases (41984 B)
  __shared__ short as_s[128 * ASP];

  int tid = threadIdx.x;
  int lane = tid & 63;
  int wv = tid >> 6;                  // 0..7
  int l15 = lane & 15;
  int quad = lane >> 4;

  // stage fragments + folded biases via DMA (2624 x 16B)
#pragma unroll
  for (int i = 0; i < 5; i++)
    gl_lds16(ewf + (i * 512 + tid) * 8, &wbuf[(i * 512 + tid) * 8]);
  if (tid < 64)
    gl_lds16(ewf + (2560 + tid) * 8, &wbuf[(2560 + tid) * 8]);

  const short* w1f = wbuf;
  const short* w2f = wbuf + 4096;

  int rowbase = blockIdx.x * 128 + wv * 16;

  // A fragment straight from global fp32 (packed cvt)
  short8 af;
  {
    const float* xp = xin + (size_t)(rowbase + l15) * 32 + quad * 8;
    float4 v0 = *(const float4*)xp;
    float4 v1 = *(const float4*)(xp + 4);
    union { short8 s; unsigned u[4]; } a;
    a.u[0] = f2bf2(v0.x, v0.y); a.u[1] = f2bf2(v0.z, v0.w);
    a.u[2] = f2bf2(v1.x, v1.y); a.u[3] = f2bf2(v1.z, v1.w);
    af = a.s;
  }

  __syncthreads();   // DMA done

  const float* fb = (const float*)(wbuf + 20480);
  float b1j[8], b2j[8];
#pragma unroll
  for (int c = 0; c < 8; c++) {
    b1j[c] = fb[c * 16 + l15];
    b2j[c] = fb[128 + c * 16 + l15];
  }

  // GEMM1: K=32, 8 col-tiles; bias pre-loaded into accumulator
  floatx4 acc[8];
#pragma unroll
  for (int c = 0; c < 8; c++) {
    floatx4 z = {b1j[c], b1j[c], b1j[c], b1j[c]};
    acc[c] = __builtin_amdgcn_mfma_f32_16x16x32_bf16(
        af, *(const short8*)&w1f[(c * 64 + lane) * 8], z, 0, 0, 0);
  }

  // epilogue1: relu only (BN folded into W2'), packed cvt, b16 stores
#pragma unroll
  for (int c = 0; c < 8; c++)
#pragma unroll
    for (int r = 0; r < 4; r += 2) {
      unsigned pk = f2bf2(fmaxf(acc[c][r], 0.f), fmaxf(acc[c][r + 1], 0.f));
      int base = (wv * 16 + quad * 4 + r) * ASP + c * 16 + l15;
      as_s[base] = (short)(pk & 0xffff);
      as_s[base + ASP] = (short)(pk >> 16);
    }

  // GEMM2: K=128 in 4 steps; b2' pre-loaded into accumulator
  floatx4 acc2[8];
#pragma unroll
  for (int c = 0; c < 8; c++) acc2[c] = (floatx4){b2j[c], b2j[c], b2j[c], b2j[c]};
#pragma unroll
  for (int s = 0; s < 4; s++) {
    short8 a2 = *(const short8*)&as_s[(wv * 16 + l15) * ASP + s * 32 + quad * 8];
#pragma unroll
    for (int c = 0; c < 8; c++) {
      short8 bf = *(const short8*)&w2f[((s * 8 + c) * 64 + lane) * 8];
      acc2[c] = __builtin_amdgcn_mfma_f32_16x16x32_bf16(a2, bf, acc2[c], 0, 0, 0);
    }
  }

  // cosine: row pairs (2e,2e+1) in same lane, regs (2i,2i+1)
  float p[2], qq[2], rr[2];
#pragma unroll
  for (int i = 0; i < 2; i++) { p[i] = 0.f; qq[i] = 0.f; rr[i] = 0.f; }
#pragma unroll
  for (int c = 0; c < 8; c++)
#pragma unroll
    for (int i = 0; i < 2; i++) {
      float hx = acc2[c][2 * i];
      float hy = acc2[c][2 * i + 1];
      p[i]  += hx * hy;
      qq[i] += hx * hx;
      rr[i] += hy * hy;
    }
#pragma unroll
  for (int m = 1; m < 16; m <<= 1)
#pragma unroll
    for (int i = 0; i < 2; i++) {
      p[i]  += __shfl_xor(p[i], m, 64);
      qq[i] += __shfl_xor(qq[i], m, 64);
      rr[i] += __shfl_xor(rr[i], m, 64);
    }
  if (l15 == 0) {
#pragma unroll
    for (int i = 0; i < 2; i++) {
      int row = rowbase + quad * 4 + 2 * i;
      int e = row >> 1;
      float n1 = fmaxf(sqrtf(qq[i]), 1e-8f);
      float n2 = fmaxf(sqrtf(rr[i]), 1e-8f);
      float w = (p[i] / (n1 * n2) + 1.f) * 0.5f;
      ew_out[e] = w;
      atomicAdd(deg + eidx[e], w);
      atomicAdd(cnt + eidx[EE + e], 1);
    }
  }
}

// ---------------- features fp32 -> bf16 ----------------
__global__ __launch_bounds__(256) void fconv_kernel(const float* __restrict__ src,
                                                    unsigned short* __restrict__ dst) {
  size_t i = ((size_t)blockIdx.x * 256 + threadIdx.x) * 8;
  float4 a = *(const float4*)(src + i);
  float4 b = *(const float4*)(src + i + 4);
  union { ushort8 s; unsigned u[4]; } o;
  o.u[0] = f2bf2(a.x, a.y); o.u[1] = f2bf2(a.z, a.w);
  o.u[2] = f2bf2(b.x, b.y); o.u[3] = f2bf2(b.z, b.w);
  *(ushort8*)(dst + i) = o.s;
}

// ---------------- weights: transpose 256x256 chunks, fp32 -> bf16 ----------------
__global__ __launch_bounds__(256) void wconv_kernel(
    const float* __restrict__ cheb_w, const float* __restrict__ cls_w1,
    unsigned short* __restrict__ wtc, unsigned short* __restrict__ clsT)
{
  __shared__ unsigned short tile[64][80];
  int z = blockIdx.z;
  const float* src; unsigned short* dst; int ldk;
  if (z < 12) {
    int l = z / 3, c = z % 3;
    src = cheb_w + (size_t)z * 65536;
    dst = wtc + (size_t)l * 196608 + c * 256;
    ldk = 768;
  } else {
    int c = z - 12;
    src = cls_w1 + (size_t)c * 65536;
    dst = clsT + c * 256;
    ldk = 1024;
  }
  int t = threadIdx.x;
  int k0 = blockIdx.x * 64, n0 = blockIdx.y * 64;
#pragma unroll
  for (int pass = 0; pass < 4; pass++) {
    int kk = pass * 16 + (t >> 4);
    int nl = (t & 15) * 4;
    float4 v = *(const float4*)(src + (size_t)(k0 + kk) * 256 + n0 + nl);
    tile[nl + 0][kk] = f2bf(v.x);
    tile[nl + 1][kk] = f2bf(v.y);
    tile[nl + 2][kk] = f2bf(v.z);
    tile[nl + 3][kk] = f2bf(v.w);
  }
  __syncthreads();
  int nl = t >> 2, kc = (t & 3) * 16;
  ushort8 v0 = *(const ushort8*)&tile[nl][kc];
  ushort8 v1 = *(const ushort8*)&tile[nl][kc + 8];
  unsigned short* dp = dst + (size_t)(n0 + nl) * ldk + k0 + kc;
  *(ushort8*)dp = v0;
  *(ushort8*)(dp + 8) = v1;
}

// ---------------- degree -> D^-1/2 ----------------
__global__ void dis_kernel(const float* __restrict__ deg, float* __restrict__ dis) {
  int i = blockIdx.x * 256 + threadIdx.x;
  if (i < NN) {
    float d = deg[i];
    dis[i] = d > 0.f ? 1.f / sqrtf(fmaxf(d, 1e-30f)) : 0.f;
  }
}

// ---------------- exclusive scan of in-degree counts (padded to x4) ----------------
__global__ __launch_bounds__(1024) void scan_kernel(const int* __restrict__ cnt, int* __restrict__ ptr) {
  __shared__ int sums[1024];
  int tid = threadIdx.x;
  const int n = NN;
  const int chunk = (n + 1023) / 1024;
  int base = tid * chunk;
  int s = 0;
  for (int i = 0; i < chunk; i++) {
    int idx = base + i;
    if (idx < n) s += (cnt[idx] + 3) & ~3;
  }
  sums[tid] = s;
  __syncthreads();
  for (int off = 1; off < 1024; off <<= 1) {
    int v = (tid >= off) ? sums[tid - off] : 0;
    __syncthreads();
    sums[tid] += v;
    __syncthreads();
  }
  int run = (tid == 0) ? 0 : sums[tid - 1];
  for (int i = 0; i < chunk; i++) {
    int idx = base + i;
    if (idx < n) { ptr[idx] = run; run += (cnt[idx] + 3) & ~3; }
  }
  if (tid == 1023) ptr[n] = run;
}

// ---------------- CSR fill (pad slots pre-zeroed) ----------------
__global__ void fill_kernel(const int* __restrict__ eidx, const float* __restrict__ ew,
                            const float* __restrict__ dis, const int* __restrict__ ptr,
                            int* __restrict__ fill, int* __restrict__ cidx, float* __restrict__ cval) {
  int e = blockIdx.x * 256 + threadIdx.x;
  if (e < EE) {
    int r = eidx[e], c = eidx[EE + e];
    float nv = -dis[r] * ew[e] * dis[c];
    int pos = ptr[c] + atomicAdd(&fill[c], 1);
    cidx[pos] = r;
    cval[pos] = nv;
  }
}

// ---------------- sparse prop (bf16): y[c] = alpha*sum val*x[row] (- sub[c]) ----------------
// half-wave (32 lanes) per node; segments padded to x4 -> int4/float4 CSR loads, no remainder
__global__ __launch_bounds__(256) void prop_kernel(
    const unsigned short* __restrict__ x, int ldx,
    const int* __restrict__ cidx, const float* __restrict__ cval,
    const int* __restrict__ ptr,
    unsigned short* __restrict__ y, int ldy,
    float alpha, const unsigned short* __restrict__ sub, int ldsub)
{
  int c = blockIdx.x * 8 + (threadIdx.x >> 5);
  int lane5 = threadIdx.x & 31;
  int d = lane5 * 8;
  int p0 = ptr[c], p1 = ptr[c + 1];
  float a[8] = {0.f, 0.f, 0.f, 0.f, 0.f, 0.f, 0.f, 0.f};
  for (int p = p0; p < p1; p += 4) {
    int4 r4 = *(const int4*)(cidx + p);
    float4 w4 = *(const float4*)(cval + p);
    ushort8 v0 = *(const ushort8*)(x + (size_t)r4.x * ldx + d);
    ushort8 v1 = *(const ushort8*)(x + (size_t)r4.y * ldx + d);
    ushort8 v2 = *(const ushort8*)(x + (size_t)r4.z * ldx + d);
    ushort8 v3 = *(const ushort8*)(x + (size_t)r4.w * ldx + d);
#pragma unroll
    for (int j = 0; j < 8; j++)
      a[j] += w4.x * bf2f(v0[j]) + w4.y * bf2f(v1[j]) + w4.z * bf2f(v2[j]) + w4.w * bf2f(v3[j]);
  }
  union { ushort8 s; unsigned u[4]; } o;
  if (sub) {
    ushort8 sv = *(const ushort8*)(sub + (size_t)c * ldsub + d);
#pragma unroll
    for (int j = 0; j < 8; j += 2)
      o.u[j >> 1] = f2bf2(alpha * a[j] - bf2f(sv[j]), alpha * a[j + 1] - bf2f(sv[j + 1]));
  } else {
#pragma unroll
    for (int j = 0; j < 8; j += 2)
      o.u[j >> 1] = f2bf2(a[j], a[j + 1]);
  }
  *(ushort8*)(y + (size_t)c * ldy + d) = o.s;
}

// ---------------- bf16 MFMA GEMM: C = post( sum_c A_c @ B_c ) ----------------
__global__ __launch_bounds__(256, 2) void mgemm_kernel(
    const unsigned short* A0, const unsigned short* A1,
    const unsigned short* A2, const unsigned short* A3,
    int l0, int l1, int l2, int l3, int nchunks,
    const unsigned short* __restrict__ BT, int ldbt,
    unsigned short* __restrict__ Cb, float* __restrict__ Cf, int ldc, int M,
    const float* __restrict__ bias, const float* __restrict__ bng,
    const float* __restrict__ bnb)
{
  __shared__ short As[4 * 64 * 8];
  __shared__ short Bs[4 * 128 * 8];
  int tid = threadIdx.x;
  int lane = tid & 63;
  int wv = tid >> 6;
  int l15 = lane & 15, quad = lane >> 4;
  int wr = wv >> 1, wc = wv & 1;
  int m0 = blockIdx.x * 64, n0 = blockIdx.y * 128;

  const unsigned short* Ap[4] = {A0, A1, A2, A3};
  int Al[4] = {l0, l1, l2, l3};

  int arow = tid & 63, ac = tid >> 6;
  int brow = tid & 127, bc = tid >> 7;

  floatx4 acc[2][4];
#pragma unroll
  for (int mi = 0; mi < 2; mi++)
#pragma unroll
    for (int nj = 0; nj < 4; nj++) acc[mi][nj] = (floatx4){0.f, 0.f, 0.f, 0.f};

  for (int c = 0; c < nchunks; c++) {
    const unsigned short* Abase = Ap[c] + (size_t)(m0 + arow) * Al[c] + ac * 8;
    const unsigned short* Bbase = BT + (size_t)(n0 + brow) * ldbt + c * 256 + bc * 8;
#pragma unroll 1
    for (int kb = 0; kb < 256; kb += 32) {
      __syncthreads();
      gl_lds16(Abase + kb, &As[tid * 8]);
      gl_lds16(Bbase + kb, &Bs[tid * 8]);
      gl_lds16(Bbase + 16 + kb, &Bs[(tid + 256) * 8]);
      __syncthreads();
      short8 af[2], bfv[4];
#pragma unroll
      for (int mi = 0; mi < 2; mi++)
        af[mi] = *(const short8*)&As[(quad * 64 + wr * 32 + mi * 16 + l15) * 8];
#pragma unroll
      for (int nj = 0; nj < 4; nj++)
        bfv[nj] = *(const short8*)&Bs[(quad * 128 + wc * 64 + nj * 16 + l15) * 8];
#pragma unroll
      for (int nj = 0; nj < 4; nj++)
#pragma unroll
        for (int mi = 0; mi < 2; mi++)
          acc[mi][nj] = __builtin_amdgcn_mfma_f32_16x16x32_bf16(af[mi], bfv[nj], acc[mi][nj], 0, 0, 0);
    }
  }

  if (Cb) {
#pragma unroll
    for (int mi = 0; mi < 2; mi++)
#pragma unroll
      for (int r = 0; r < 4; r++) {
        int row = m0 + wr * 32 + mi * 16 + quad * 4 + r;
        if (row < M) {
#pragma unroll
          for (int nj = 0; nj < 4; nj++) {
            int col = n0 + wc * 64 + nj * 16 + l15;
            Cb[(size_t)row * ldc + col] = (unsigned short)f2bf(fmaxf(acc[mi][nj][r], 0.f));
          }
        }
      }
  } else {
    float bs[4], g[4], bb[4];
#pragma unroll
    for (int nj = 0; nj < 4; nj++) {
      int col = n0 + wc * 64 + nj * 16 + l15;
      bs[nj] = bias[col]; g[nj] = bng[col] * RSBN; bb[nj] = bnb[col];
    }
#pragma unroll
    for (int mi = 0; mi < 2; mi++)
#pragma unroll
      for (int r = 0; r < 4; r++) {
        int row = m0 + wr * 32 + mi * 16 + quad * 4 + r;
        if (row < M) {
#pragma unroll
          for (int nj = 0; nj < 4; nj++) {
            int col = n0 + wc * 64 + nj * 16 + l15;
            float v = fmaxf(acc[mi][nj][r] + bs[nj], 0.f) * g[nj] + bb[nj];
            Cf[(size_t)row * ldc + col] = v;
          }
        }
      }
  }
}

// ---------------- final 256x2 matvec per node ----------------
__global__ __launch_bounds__(256) void logit_kernel(
    const float* __restrict__ z, const float* __restrict__ w2,
    const float* __restrict__ b2, float* __restrict__ out)
{
  int node = blockIdx.x * 4 + (threadIdx.x >> 6);
  if (node >= NN) return;
  int lane = threadIdx.x & 63;
  int k = lane * 4;
  float4 zv = *(const float4*)(z + (size_t)node * 256 + k);
  float4 wa = *(const float4*)(w2 + k * 2);
  float4 wb = *(const float4*)(w2 + k * 2 + 4);
  float a0 = zv.x * wa.x + zv.y * wa.z + zv.z * wb.x + zv.w * wb.z;
  float a1 = zv.x * wa.y + zv.y * wa.w + zv.z * wb.y + zv.w * wb.w;
#pragma unroll
  for (int m = 32; m >= 1; m >>= 1) {
    a0 += __shfl_xor(a0, m, 64);
    a1 += __shfl_xor(a1, m, 64);
  }
  if (lane == 0) {
    out[(size_t)node * 2]     = a0 + b2[0];
    out[(size_t)node * 2 + 1] = a1 + b2[1];
  }
}

extern "C" void kernel_launch(void* const* d_in, const int* in_sizes, int n_in,
                              void* d_out, int out_size, void* d_ws, size_t ws_size,
                              hipStream_t stream) {
  const float* features = (const float*)d_in[0];
  const int*   eidx     = (const int*)d_in[1];
  const float* xin      = (const float*)d_in[2];
  const float* cheb_w   = (const float*)d_in[3];
  const float* en_w1    = (const float*)d_in[4];
  const float* en_b1    = (const float*)d_in[5];
  const float* en_g1    = (const float*)d_in[6];
  const float* en_be1   = (const float*)d_in[7];
  const float* en_w2    = (const float*)d_in[8];
  const float* en_b2    = (const float*)d_in[9];
  const float* cls_w1   = (const float*)d_in[10];
  const float* cls_b1   = (const float*)d_in[11];
  const float* cls_g    = (const float*)d_in[12];
  const float* cls_b    = (const float*)d_in[13];
  const float* cls_w2   = (const float*)d_in[14];
  const float* cls_b2   = (const float*)d_in[15];
  float* out = (float*)d_out;

  char* ws = (char*)d_ws;
  size_t off = 0;
  auto alloc = [&](size_t bytes) -> void* {
    void* p = ws + off;
    off += (bytes + 255) & ~(size_t)255;
    return p;
  };
  const int CSRN = EE + 4 * NN;   // padded CSR capacity
  float* deg  = (float*)alloc((size_t)NN * 4);
  int*   cnt  = (int*)  alloc((size_t)NN * 4);
  int*   fil  = (int*)  alloc((size_t)NN * 4);
  float* cval = (float*)alloc((size_t)CSRN * 4);
  int*   cidx = (int*)  alloc((size_t)CSRN * 4);
  size_t zero_len = off;                       // deg+cnt+fil+cval+cidx zeroed
  float* dis  = (float*)alloc((size_t)NN * 4);
  int*   ptr  = (int*)  alloc((size_t)(NN + 1) * 4);
  unsigned short* featb = (unsigned short*)alloc((size_t)NN * 256 * 2);
  unsigned short* Tx1   = (unsigned short*)alloc((size_t)NN * 256 * 2);
  unsigned short* Tx2   = (unsigned short*)alloc((size_t)NN * 256 * 2);
  unsigned short* jk    = (unsigned short*)alloc((size_t)NN * 1024 * 2);
  float* zbuf = (float*)alloc((size_t)NN * 256 * 4);
  unsigned short* wtc   = (unsigned short*)alloc((size_t)4 * 196608 * 2);
  unsigned short* clsT  = (unsigned short*)alloc((size_t)256 * 1024 * 2);
  unsigned short* ewf   = (unsigned short*)alloc((size_t)20992 * 2);
  alloc(262144);   // overread pad for GEMM tail blocks

  float* ew = out + (size_t)NN * 2;   // edge-weight output doubles as scratch

  hipMemsetAsync(deg, 0, zero_len, stream);

  ewconv_kernel<<<1, 256, 0, stream>>>(en_w1, en_w2, en_g1, en_be1, en_b1, en_b2, ewf);
  edge_kernel<<<6250, 512, 0, stream>>>(xin, eidx, ewf, ew, deg, cnt);
  fconv_kernel<<<2500, 256, 0, stream>>>(features, featb);
  wconv_kernel<<<dim3(4, 4, 16), 256, 0, stream>>>(cheb_w, cls_w1, wtc, clsT);
  dis_kernel<<<(NN + 255) / 256, 256, 0, stream>>>(deg, dis);
  scan_kernel<<<1, 1024, 0, stream>>>(cnt, ptr);
  fill_kernel<<<(EE + 255) / 256, 256, 0, stream>>>(eidx, ew, dis, ptr, fil, cidx, cval);

  dim3 ggrid(313, 2);
  for (int i = 0; i < 4; i++) {
    const unsigned short* x = (i == 0) ? featb : (jk + (size_t)(i - 1) * 256);
    int ldx = (i == 0) ? 256 : 1024;
    prop_kernel<<<2500, 256, 0, stream>>>(x, ldx, cidx, cval, ptr, Tx1, 256, 1.f, nullptr, 0);
    prop_kernel<<<2500, 256, 0, stream>>>(Tx1, 256, cidx, cval, ptr, Tx2, 256, 2.f, x, ldx);
    mgemm_kernel<<<ggrid, 256, 0, stream>>>(x, Tx1, Tx2, nullptr, ldx, 256, 256, 0, 3,
                                            wtc + (size_t)i * 196608, 768,
                                            jk + (size_t)i * 256, nullptr, 1024, NN,
                                            nullptr, nullptr, nullptr);
  }

  mgemm_kernel<<<ggrid, 256, 0, stream>>>(jk, jk + 256, jk + 512, jk + 768,
                                          1024, 1024, 1024, 1024, 4, clsT, 1024,
                                          nullptr, zbuf, 256, NN,
                                          cls_b1, cls_g, cls_b);
  logit_kernel<<<NN / 4, 256, 0, stream>>>(zbuf, cls_w2, cls_b2, out);
}

// Round 6
// 654.161 us; speedup vs baseline: 4.8367x; 1.0503x over previous
//
#include <hip/hip_runtime.h>
#include <hip/hip_bf16.h>

#define NN 20000
#define EE 400000
#define RSBN 0.9999950000374997f   // 1/sqrt(1+1e-5)

typedef __attribute__((ext_vector_type(8))) short short8;
typedef __attribute__((ext_vector_type(8))) unsigned short ushort8;
typedef __attribute__((ext_vector_type(4))) float floatx4;

__device__ __forceinline__ short f2bf(float f) {
  union { float f; unsigned u; } v; v.f = f;
  unsigned r = v.u + 0x7fffu + ((v.u >> 16) & 1u);   // RNE
  return (short)(r >> 16);
}
__device__ __forceinline__ unsigned f2bf2(float x, float y) {   // packed cvt
  union { __hip_bfloat162 h; unsigned u; } v;
  v.h = __float22bfloat162_rn(make_float2(x, y));
  return v.u;
}
__device__ __forceinline__ float bf2f(unsigned short u) {
  union { unsigned u; float f; } v; v.u = ((unsigned)u) << 16;
  return v.f;
}
__device__ __forceinline__ void gl_lds16(const void* g, void* l) {
  __builtin_amdgcn_global_load_lds(
      (const __attribute__((address_space(1))) unsigned*)g,
      (__attribute__((address_space(3))) unsigned*)l, 16, 0, 0);
}

// ---------------- edge-parser weights -> fragment-layout bf16 + folded consts ----------------
__global__ __launch_bounds__(256) void ewconv_kernel(
    const float* __restrict__ w1, const float* __restrict__ w2,
    const float* __restrict__ g1, const float* __restrict__ be1,
    const float* __restrict__ b1, const float* __restrict__ b2,
    unsigned short* __restrict__ ewf)
{
  int tid = threadIdx.x;
#pragma unroll
  for (int i = 0; i < 16; i++) {
    int idx = i * 256 + tid;
    int k = idx >> 7, n = idx & 127;
    int pos = ((n >> 4) * 64 + (k >> 3) * 16 + (n & 15)) * 8 + (k & 7);
    ewf[pos] = f2bf(w1[idx]);
  }
#pragma unroll
  for (int i = 0; i < 64; i++) {
    int idx = i * 256 + tid;
    int k = idx >> 7, n = idx & 127;
    int pos = (((k >> 5) * 8 + (n >> 4)) * 64 + ((k >> 3) & 3) * 16 + (n & 15)) * 8 + (k & 7);
    ewf[4096 + pos] = f2bf(w2[idx] * g1[k] * RSBN);   // BN scale folded
  }
  float* fb = (float*)(ewf + 20480);
  if (tid < 128) {
    fb[tid] = b1[tid];
    float acc = b2[tid];
    for (int k = 0; k < 128; k++) acc += be1[k] * w2[k * 128 + tid] * g1[k] * RSBN;
    fb[128 + tid] = acc;
  }
}

// ---------------- edge parser + edge weight (bf16 MFMA) ----------------
#define ASP 136
__global__ __launch_bounds__(512, 4) void edge_kernel(
    const float* __restrict__ xin, const int* __restrict__ eidx,
    const unsigned short* __restrict__ ewf,
    float* __restrict__ ew_out,
    float* __restrict__ deg, int* __restrict__ cnt)
{
  __shared__ short wbuf[20992];
  __shared__ short as_s[128 * ASP];

  int tid = threadIdx.x;
  int lane = tid & 63;
  int wv = tid >> 6;
  int l15 = lane & 15;
  int quad = lane >> 4;

#pragma unroll
  for (int i = 0; i < 5; i++)
    gl_lds16(ewf + (i * 512 + tid) * 8, &wbuf[(i * 512 + tid) * 8]);
  if (tid < 64)
    gl_lds16(ewf + (2560 + tid) * 8, &wbuf[(2560 + tid) * 8]);

  const short* w1f = wbuf;
  const short* w2f = wbuf + 4096;

  int rowbase = blockIdx.x * 128 + wv * 16;

  short8 af;
  {
    const float* xp = xin + (size_t)(rowbase + l15) * 32 + quad * 8;
    float4 v0 = *(const float4*)xp;
    float4 v1 = *(const float4*)(xp + 4);
    union { short8 s; unsigned u[4]; } a;
    a.u[0] = f2bf2(v0.x, v0.y); a.u[1] = f2bf2(v0.z, v0.w);
    a.u[2] = f2bf2(v1.x, v1.y); a.u[3] = f2bf2(v1.z, v1.w);
    af = a.s;
  }

  __syncthreads();

  const float* fb = (const float*)(wbuf + 20480);
  float b1j[8], b2j[8];
#pragma unroll
  for (int c = 0; c < 8; c++) {
    b1j[c] = fb[c * 16 + l15];
    b2j[c] = fb[128 + c * 16 + l15];
  }

  floatx4 acc[8];
#pragma unroll
  for (int c = 0; c < 8; c++) {
    floatx4 z = {b1j[c], b1j[c], b1j[c], b1j[c]};
    acc[c] = __builtin_amdgcn_mfma_f32_16x16x32_bf16(
        af, *(const short8*)&w1f[(c * 64 + lane) * 8], z, 0, 0, 0);
  }

#pragma unroll
  for (int c = 0; c < 8; c++)
#pragma unroll
    for (int r = 0; r < 4; r += 2) {
      unsigned pk = f2bf2(fmaxf(acc[c][r], 0.f), fmaxf(acc[c][r + 1], 0.f));
      int base = (wv * 16 + quad * 4 + r) * ASP + c * 16 + l15;
      as_s[base] = (short)(pk & 0xffff);
      as_s[base + ASP] = (short)(pk >> 16);
    }

  floatx4 acc2[8];
#pragma unroll
  for (int c = 0; c < 8; c++) acc2[c] = (floatx4){b2j[c], b2j[c], b2j[c], b2j[c]};
#pragma unroll
  for (int s = 0; s < 4; s++) {
    short8 a2 = *(const short8*)&as_s[(wv * 16 + l15) * ASP + s * 32 + quad * 8];
#pragma unroll
    for (int c = 0; c < 8; c++) {
      short8 bf = *(const short8*)&w2f[((s * 8 + c) * 64 + lane) * 8];
      acc2[c] = __builtin_amdgcn_mfma_f32_16x16x32_bf16(a2, bf, acc2[c], 0, 0, 0);
    }
  }

  float p[2], qq[2], rr[2];
#pragma unroll
  for (int i = 0; i < 2; i++) { p[i] = 0.f; qq[i] = 0.f; rr[i] = 0.f; }
#pragma unroll
  for (int c = 0; c < 8; c++)
#pragma unroll
    for (int i = 0; i < 2; i++) {
      float hx = acc2[c][2 * i];
      float hy = acc2[c][2 * i + 1];
      p[i]  += hx * hy;
      qq[i] += hx * hx;
      rr[i] += hy * hy;
    }
#pragma unroll
  for (int m = 1; m < 16; m <<= 1)
#pragma unroll
    for (int i = 0; i < 2; i++) {
      p[i]  += __shfl_xor(p[i], m, 64);
      qq[i] += __shfl_xor(qq[i], m, 64);
      rr[i] += __shfl_xor(rr[i], m, 64);
    }
  if (l15 == 0) {
#pragma unroll
    for (int i = 0; i < 2; i++) {
      int row = rowbase + quad * 4 + 2 * i;
      int e = row >> 1;
      float n1 = fmaxf(sqrtf(qq[i]), 1e-8f);
      float n2 = fmaxf(sqrtf(rr[i]), 1e-8f);
      float w = (p[i] / (n1 * n2) + 1.f) * 0.5f;
      ew_out[e] = w;
      atomicAdd(deg + eidx[e], w);
      atomicAdd(cnt + eidx[EE + e], 1);
    }
  }
}

// ---------------- features fp32 -> bf16 ----------------
__global__ __launch_bounds__(256) void fconv_kernel(const float* __restrict__ src,
                                                    unsigned short* __restrict__ dst) {
  size_t i = ((size_t)blockIdx.x * 256 + threadIdx.x) * 8;
  float4 a = *(const float4*)(src + i);
  float4 b = *(const float4*)(src + i + 4);
  union { ushort8 s; unsigned u[4]; } o;
  o.u[0] = f2bf2(a.x, a.y); o.u[1] = f2bf2(a.z, a.w);
  o.u[2] = f2bf2(b.x, b.y); o.u[3] = f2bf2(b.z, b.w);
  *(ushort8*)(dst + i) = o.s;
}

// ---------------- weights: transpose 256x256 chunks, fp32 -> bf16 ----------------
__global__ __launch_bounds__(256) void wconv_kernel(
    const float* __restrict__ cheb_w, const float* __restrict__ cls_w1,
    unsigned short* __restrict__ wtc, unsigned short* __restrict__ clsT)
{
  __shared__ unsigned short tile[64][80];
  int z = blockIdx.z;
  const float* src; unsigned short* dst; int ldk;
  if (z < 12) {
    int l = z / 3, c = z % 3;
    src = cheb_w + (size_t)z * 65536;
    dst = wtc + (size_t)l * 196608 + c * 256;
    ldk = 768;
  } else {
    int c = z - 12;
    src = cls_w1 + (size_t)c * 65536;
    dst = clsT + c * 256;
    ldk = 1024;
  }
  int t = threadIdx.x;
  int k0 = blockIdx.x * 64, n0 = blockIdx.y * 64;
#pragma unroll
  for (int pass = 0; pass < 4; pass++) {
    int kk = pass * 16 + (t >> 4);
    int nl = (t & 15) * 4;
    float4 v = *(const float4*)(src + (size_t)(k0 + kk) * 256 + n0 + nl);
    tile[nl + 0][kk] = f2bf(v.x);
    tile[nl + 1][kk] = f2bf(v.y);
    tile[nl + 2][kk] = f2bf(v.z);
    tile[nl + 3][kk] = f2bf(v.w);
  }
  __syncthreads();
  int nl = t >> 2, kc = (t & 3) * 16;
  ushort8 v0 = *(const ushort8*)&tile[nl][kc];
  ushort8 v1 = *(const ushort8*)&tile[nl][kc + 8];
  unsigned short* dp = dst + (size_t)(n0 + nl) * ldk + k0 + kc;
  *(ushort8*)dp = v0;
  *(ushort8*)(dp + 8) = v1;
}

// ---------------- degree -> D^-1/2 ----------------
__global__ void dis_kernel(const float* __restrict__ deg, float* __restrict__ dis) {
  int i = blockIdx.x * 256 + threadIdx.x;
  if (i < NN) {
    float d = deg[i];
    dis[i] = d > 0.f ? 1.f / sqrtf(fmaxf(d, 1e-30f)) : 0.f;
  }
}

// ---------------- exclusive scan of in-degree counts (padded to x4) ----------------
__global__ __launch_bounds__(1024) void scan_kernel(const int* __restrict__ cnt, int* __restrict__ ptr) {
  __shared__ int sums[1024];
  int tid = threadIdx.x;
  const int n = NN;
  const int chunk = (n + 1023) / 1024;
  int base = tid * chunk;
  int s = 0;
  for (int i = 0; i < chunk; i++) {
    int idx = base + i;
    if (idx < n) s += (cnt[idx] + 3) & ~3;
  }
  sums[tid] = s;
  __syncthreads();
  for (int off = 1; off < 1024; off <<= 1) {
    int v = (tid >= off) ? sums[tid - off] : 0;
    __syncthreads();
    sums[tid] += v;
    __syncthreads();
  }
  int run = (tid == 0) ? 0 : sums[tid - 1];
  for (int i = 0; i < chunk; i++) {
    int idx = base + i;
    if (idx < n) { ptr[idx] = run; run += (cnt[idx] + 3) & ~3; }
  }
  if (tid == 1023) ptr[n] = run;
}

// ---------------- CSR fill (pad slots pre-zeroed) ----------------
__global__ void fill_kernel(const int* __restrict__ eidx, const float* __restrict__ ew,
                            const float* __restrict__ dis, const int* __restrict__ ptr,
                            int* __restrict__ fill, int* __restrict__ cidx, float* __restrict__ cval) {
  int e = blockIdx.x * 256 + threadIdx.x;
  if (e < EE) {
    int r = eidx[e], c = eidx[EE + e];
    float nv = -dis[r] * ew[e] * dis[c];
    int pos = ptr[c] + atomicAdd(&fill[c], 1);
    cidx[pos] = r;
    cval[pos] = nv;
  }
}

// ---------------- sparse prop (bf16, XCD-sliced): y[c] = alpha*sum val*x[row] (- sub[c]) ----
// XCD-locality: blockIdx&7 ~ XCD (round-robin heuristic). Column slice = (blockIdx&7)>>1
// (4 slices x 64ch = 128B, line-aligned) -> per-XCD gather footprint 20000*128B = 2.5 MB,
// L2-resident. 8 lanes per node, 8ch x bf16 = 16B per lane. Segments padded to x4.
__global__ __launch_bounds__(256) void prop_kernel(
    const unsigned short* __restrict__ x, int ldx,
    const int* __restrict__ cidx, const float* __restrict__ cval,
    const int* __restrict__ ptr,
    unsigned short* __restrict__ y, int ldy,
    float alpha, const unsigned short* __restrict__ sub, int ldsub)
{
  int sliceid = blockIdx.x & 7;
  int colslice = sliceid >> 1;                       // 0..3
  int chunk = (blockIdx.x >> 3) * 2 + (sliceid & 1); // 0..625
  int c = chunk * 32 + (threadIdx.x >> 3);
  if (c >= NN) return;
  int d = colslice * 64 + (threadIdx.x & 7) * 8;
  int p0 = ptr[c], p1 = ptr[c + 1];
  float a[8] = {0.f, 0.f, 0.f, 0.f, 0.f, 0.f, 0.f, 0.f};
  for (int p = p0; p < p1; p += 4) {
    int4 r4 = *(const int4*)(cidx + p);
    float4 w4 = *(const float4*)(cval + p);
    ushort8 v0 = *(const ushort8*)(x + (size_t)r4.x * ldx + d);
    ushort8 v1 = *(const ushort8*)(x + (size_t)r4.y * ldx + d);
    ushort8 v2 = *(const ushort8*)(x + (size_t)r4.z * ldx + d);
    ushort8 v3 = *(const ushort8*)(x + (size_t)r4.w * ldx + d);
#pragma unroll
    for (int j = 0; j < 8; j++)
      a[j] += w4.x * bf2f(v0[j]) + w4.y * bf2f(v1[j]) + w4.z * bf2f(v2[j]) + w4.w * bf2f(v3[j]);
  }
  union { ushort8 s; unsigned u[4]; } o;
  if (sub) {
    ushort8 sv = *(const ushort8*)(sub + (size_t)c * ldsub + d);
#pragma unroll
    for (int j = 0; j < 8; j += 2)
      o.u[j >> 1] = f2bf2(alpha * a[j] - bf2f(sv[j]), alpha * a[j + 1] - bf2f(sv[j + 1]));
  } else {
#pragma unroll
    for (int j = 0; j < 8; j += 2)
      o.u[j >> 1] = f2bf2(a[j], a[j + 1]);
  }
  *(ushort8*)(y + (size_t)c * ldy + d) = o.s;
}

// ---------------- bf16 MFMA GEMM: C = post( sum_c A_c @ B_c ) ----------------
__global__ __launch_bounds__(256, 2) void mgemm_kernel(
    const unsigned short* A0, const unsigned short* A1,
    const unsigned short* A2, const unsigned short* A3,
    int l0, int l1, int l2, int l3, int nchunks,
    const unsigned short* __restrict__ BT, int ldbt,
    unsigned short* __restrict__ Cb, float* __restrict__ Cf, int ldc, int M,
    const float* __restrict__ bias, const float* __restrict__ bng,
    const float* __restrict__ bnb)
{
  __shared__ short As[4 * 64 * 8];
  __shared__ short Bs[4 * 128 * 8];
  int tid = threadIdx.x;
  int lane = tid & 63;
  int wv = tid >> 6;
  int l15 = lane & 15, quad = lane >> 4;
  int wr = wv >> 1, wc = wv & 1;
  int m0 = blockIdx.x * 64, n0 = blockIdx.y * 128;

  const unsigned short* Ap[4] = {A0, A1, A2, A3};
  int Al[4] = {l0, l1, l2, l3};

  int arow = tid & 63, ac = tid >> 6;
  int brow = tid & 127, bc = tid >> 7;

  floatx4 acc[2][4];
#pragma unroll
  for (int mi = 0; mi < 2; mi++)
#pragma unroll
    for (int nj = 0; nj < 4; nj++) acc[mi][nj] = (floatx4){0.f, 0.f, 0.f, 0.f};

  for (int c = 0; c < nchunks; c++) {
    const unsigned short* Abase = Ap[c] + (size_t)(m0 + arow) * Al[c] + ac * 8;
    const unsigned short* Bbase = BT + (size_t)(n0 + brow) * ldbt + c * 256 + bc * 8;
#pragma unroll 1
    for (int kb = 0; kb < 256; kb += 32) {
      __syncthreads();
      gl_lds16(Abase + kb, &As[tid * 8]);
      gl_lds16(Bbase + kb, &Bs[tid * 8]);
      gl_lds16(Bbase + 16 + kb, &Bs[(tid + 256) * 8]);
      __syncthreads();
      short8 af[2], bfv[4];
#pragma unroll
      for (int mi = 0; mi < 2; mi++)
        af[mi] = *(const short8*)&As[(quad * 64 + wr * 32 + mi * 16 + l15) * 8];
#pragma unroll
      for (int nj = 0; nj < 4; nj++)
        bfv[nj] = *(const short8*)&Bs[(quad * 128 + wc * 64 + nj * 16 + l15) * 8];
#pragma unroll
      for (int nj = 0; nj < 4; nj++)
#pragma unroll
        for (int mi = 0; mi < 2; mi++)
          acc[mi][nj] = __builtin_amdgcn_mfma_f32_16x16x32_bf16(af[mi], bfv[nj], acc[mi][nj], 0, 0, 0);
    }
  }

  if (Cb) {
#pragma unroll
    for (int mi = 0; mi < 2; mi++)
#pragma unroll
      for (int r = 0; r < 4; r++) {
        int row = m0 + wr * 32 + mi * 16 + quad * 4 + r;
        if (row < M) {
#pragma unroll
          for (int nj = 0; nj < 4; nj++) {
            int col = n0 + wc * 64 + nj * 16 + l15;
            Cb[(size_t)row * ldc + col] = (unsigned short)f2bf(fmaxf(acc[mi][nj][r], 0.f));
          }
        }
      }
  } else {
    float bs[4], g[4], bb[4];
#pragma unroll
    for (int nj = 0; nj < 4; nj++) {
      int col = n0 + wc * 64 + nj * 16 + l15;
      bs[nj] = bias[col]; g[nj] = bng[col] * RSBN; bb[nj] = bnb[col];
    }
#pragma unroll
    for (int mi = 0; mi < 2; mi++)
#pragma unroll
      for (int r = 0; r < 4; r++) {
        int row = m0 + wr * 32 + mi * 16 + quad * 4 + r;
        if (row < M) {
#pragma unroll
          for (int nj = 0; nj < 4; nj++) {
            int col = n0 + wc * 64 + nj * 16 + l15;
            float v = fmaxf(acc[mi][nj][r] + bs[nj], 0.f) * g[nj] + bb[nj];
            Cf[(size_t)row * ldc + col] = v;
          }
        }
      }
  }
}

// ---------------- final 256x2 matvec per node ----------------
__global__ __launch_bounds__(256) void logit_kernel(
    const float* __restrict__ z, const float* __restrict__ w2,
    const float* __restrict__ b2, float* __restrict__ out)
{
  int node = blockIdx.x * 4 + (threadIdx.x >> 6);
  if (node >= NN) return;
  int lane = threadIdx.x & 63;
  int k = lane * 4;
  float4 zv = *(const float4*)(z + (size_t)node * 256 + k);
  float4 wa = *(const float4*)(w2 + k * 2);
  float4 wb = *(const float4*)(w2 + k * 2 + 4);
  float a0 = zv.x * wa.x + zv.y * wa.z + zv.z * wb.x + zv.w * wb.z;
  float a1 = zv.x * wa.y + zv.y * wa.w + zv.z * wb.y + zv.w * wb.w;
#pragma unroll
  for (int m = 32; m >= 1; m >>= 1) {
    a0 += __shfl_xor(a0, m, 64);
    a1 += __shfl_xor(a1, m, 64);
  }
  if (lane == 0) {
    out[(size_t)node * 2]     = a0 + b2[0];
    out[(size_t)node * 2 + 1] = a1 + b2[1];
  }
}

extern "C" void kernel_launch(void* const* d_in, const int* in_sizes, int n_in,
                              void* d_out, int out_size, void* d_ws, size_t ws_size,
                              hipStream_t stream) {
  const float* features = (const float*)d_in[0];
  const int*   eidx     = (const int*)d_in[1];
  const float* xin      = (const float*)d_in[2];
  const float* cheb_w   = (const float*)d_in[3];
  const float* en_w1    = (const float*)d_in[4];
  const float* en_b1    = (const float*)d_in[5];
  const float* en_g1    = (const float*)d_in[6];
  const float* en_be1   = (const float*)d_in[7];
  const float* en_w2    = (const float*)d_in[8];
  const float* en_b2    = (const float*)d_in[9];
  const float* cls_w1   = (const float*)d_in[10];
  const float* cls_b1   = (const float*)d_in[11];
  const float* cls_g    = (const float*)d_in[12];
  const float* cls_b    = (const float*)d_in[13];
  const float* cls_w2   = (const float*)d_in[14];
  const float* cls_b2   = (const float*)d_in[15];
  float* out = (float*)d_out;

  char* ws = (char*)d_ws;
  size_t off = 0;
  auto alloc = [&](size_t bytes) -> void* {
    void* p = ws + off;
    off += (bytes + 255) & ~(size_t)255;
    return p;
  };
  const int CSRN = EE + 4 * NN;   // padded CSR capacity
  float* deg  = (float*)alloc((size_t)NN * 4);
  int*   cnt  = (int*)  alloc((size_t)NN * 4);
  int*   fil  = (int*)  alloc((size_t)NN * 4);
  float* cval = (float*)alloc((size_t)CSRN * 4);
  int*   cidx = (int*)  alloc((size_t)CSRN * 4);
  size_t zero_len = off;                       // deg+cnt+fil+cval+cidx zeroed
  float* dis  = (float*)alloc((size_t)NN * 4);
  int*   ptr  = (int*)  alloc((size_t)(NN + 1) * 4);
  unsigned short* featb = (unsigned short*)alloc((size_t)NN * 256 * 2);
  unsigned short* Tx1   = (unsigned short*)alloc((size_t)NN * 256 * 2);
  unsigned short* Tx2   = (unsigned short*)alloc((size_t)NN * 256 * 2);
  unsigned short* jk    = (unsigned short*)alloc((size_t)NN * 1024 * 2);
  float* zbuf = (float*)alloc((size_t)NN * 256 * 4);
  unsigned short* wtc   = (unsigned short*)alloc((size_t)4 * 196608 * 2);
  unsigned short* clsT  = (unsigned short*)alloc((size_t)256 * 1024 * 2);
  unsigned short* ewf   = (unsigned short*)alloc((size_t)20992 * 2);
  alloc(262144);   // overread pad for GEMM tail blocks

  float* ew = out + (size_t)NN * 2;   // edge-weight output doubles as scratch

  hipMemsetAsync(deg, 0, zero_len, stream);

  ewconv_kernel<<<1, 256, 0, stream>>>(en_w1, en_w2, en_g1, en_be1, en_b1, en_b2, ewf);
  edge_kernel<<<6250, 512, 0, stream>>>(xin, eidx, ewf, ew, deg, cnt);
  fconv_kernel<<<2500, 256, 0, stream>>>(features, featb);
  wconv_kernel<<<dim3(4, 4, 16), 256, 0, stream>>>(cheb_w, cls_w1, wtc, clsT);
  dis_kernel<<<(NN + 255) / 256, 256, 0, stream>>>(deg, dis);
  scan_kernel<<<1, 1024, 0, stream>>>(cnt, ptr);
  fill_kernel<<<(EE + 255) / 256, 256, 0, stream>>>(eidx, ew, dis, ptr, fil, cidx, cval);

  dim3 ggrid(313, 2);
  for (int i = 0; i < 4; i++) {
    const unsigned short* x = (i == 0) ? featb : (jk + (size_t)(i - 1) * 256);
    int ldx = (i == 0) ? 256 : 1024;
    prop_kernel<<<2504, 256, 0, stream>>>(x, ldx, cidx, cval, ptr, Tx1, 256, 1.f, nullptr, 0);
    prop_kernel<<<2504, 256, 0, stream>>>(Tx1, 256, cidx, cval, ptr, Tx2, 256, 2.f, x, ldx);
    mgemm_kernel<<<ggrid, 256, 0, stream>>>(x, Tx1, Tx2, nullptr, ldx, 256, 256, 0, 3,
                                            wtc + (size_t)i * 196608, 768,
                                            jk + (size_t)i * 256, nullptr, 1024, NN,
                                            nullptr, nullptr, nullptr);
  }

  mgemm_kernel<<<ggrid, 256, 0, stream>>>(jk, jk + 256, jk + 512, jk + 768,
                                          1024, 1024, 1024, 1024, 4, clsT, 1024,
                                          nullptr, zbuf, 256, NN,
                                          cls_b1, cls_g, cls_b);
  logit_kernel<<<NN / 4, 256, 0, stream>>>(zbuf, cls_w2, cls_b2, out);
}

// Round 7
// 644.768 us; speedup vs baseline: 4.9072x; 1.0146x over previous
//
#include <hip/hip_runtime.h>
#include <hip/hip_bf16.h>

#define NN 20000
#define EE 400000
#define RSBN 0.9999950000374997f   // 1/sqrt(1+1e-5)

typedef __attribute__((ext_vector_type(8))) short short8;
typedef __attribute__((ext_vector_type(8))) unsigned short ushort8;
typedef __attribute__((ext_vector_type(4))) float floatx4;

__device__ __forceinline__ short f2bf(float f) {
  union { float f; unsigned u; } v; v.f = f;
  unsigned r = v.u + 0x7fffu + ((v.u >> 16) & 1u);   // RNE
  return (short)(r >> 16);
}
__device__ __forceinline__ unsigned f2bf2(float x, float y) {   // packed cvt
  union { __hip_bfloat162 h; unsigned u; } v;
  v.h = __float22bfloat162_rn(make_float2(x, y));
  return v.u;
}
__device__ __forceinline__ float bf2f(unsigned short u) {
  union { unsigned u; float f; } v; v.u = ((unsigned)u) << 16;
  return v.f;
}
__device__ __forceinline__ void gl_lds16(const void* g, void* l) {
  __builtin_amdgcn_global_load_lds(
      (const __attribute__((address_space(1))) unsigned*)g,
      (__attribute__((address_space(3))) unsigned*)l, 16, 0, 0);
}

// ---------------- edge-parser weights -> fragment-layout bf16 + folded consts ----------------
__global__ __launch_bounds__(256) void ewconv_kernel(
    const float* __restrict__ w1, const float* __restrict__ w2,
    const float* __restrict__ g1, const float* __restrict__ be1,
    const float* __restrict__ b1, const float* __restrict__ b2,
    unsigned short* __restrict__ ewf)
{
  int tid = threadIdx.x;
#pragma unroll
  for (int i = 0; i < 16; i++) {
    int idx = i * 256 + tid;
    int k = idx >> 7, n = idx & 127;
    int pos = ((n >> 4) * 64 + (k >> 3) * 16 + (n & 15)) * 8 + (k & 7);
    ewf[pos] = f2bf(w1[idx]);
  }
#pragma unroll
  for (int i = 0; i < 64; i++) {
    int idx = i * 256 + tid;
    int k = idx >> 7, n = idx & 127;
    int pos = (((k >> 5) * 8 + (n >> 4)) * 64 + ((k >> 3) & 3) * 16 + (n & 15)) * 8 + (k & 7);
    ewf[4096 + pos] = f2bf(w2[idx] * g1[k] * RSBN);   // BN scale folded
  }
  float* fb = (float*)(ewf + 20480);
  if (tid < 128) {
    fb[tid] = b1[tid];
    float acc = b2[tid];
    for (int k = 0; k < 128; k++) acc += be1[k] * w2[k * 128 + tid] * g1[k] * RSBN;
    fb[128 + tid] = acc;
  }
}

// ---------------- edge parser + edge weight (bf16 MFMA) ----------------
#define ASP 136
__global__ __launch_bounds__(512, 4) void edge_kernel(
    const float* __restrict__ xin, const int* __restrict__ eidx,
    const unsigned short* __restrict__ ewf,
    float* __restrict__ ew_out,
    float* __restrict__ deg, int* __restrict__ cnt)
{
  __shared__ short wbuf[20992];
  __shared__ short as_s[128 * ASP];

  int tid = threadIdx.x;
  int lane = tid & 63;
  int wv = tid >> 6;
  int l15 = lane & 15;
  int quad = lane >> 4;

#pragma unroll
  for (int i = 0; i < 5; i++)
    gl_lds16(ewf + (i * 512 + tid) * 8, &wbuf[(i * 512 + tid) * 8]);
  if (tid < 64)
    gl_lds16(ewf + (2560 + tid) * 8, &wbuf[(2560 + tid) * 8]);

  const short* w1f = wbuf;
  const short* w2f = wbuf + 4096;

  int rowbase = blockIdx.x * 128 + wv * 16;

  short8 af;
  {
    const float* xp = xin + (size_t)(rowbase + l15) * 32 + quad * 8;
    float4 v0 = *(const float4*)xp;
    float4 v1 = *(const float4*)(xp + 4);
    union { short8 s; unsigned u[4]; } a;
    a.u[0] = f2bf2(v0.x, v0.y); a.u[1] = f2bf2(v0.z, v0.w);
    a.u[2] = f2bf2(v1.x, v1.y); a.u[3] = f2bf2(v1.z, v1.w);
    af = a.s;
  }

  __syncthreads();

  const float* fb = (const float*)(wbuf + 20480);
  float b1j[8], b2j[8];
#pragma unroll
  for (int c = 0; c < 8; c++) {
    b1j[c] = fb[c * 16 + l15];
    b2j[c] = fb[128 + c * 16 + l15];
  }

  floatx4 acc[8];
#pragma unroll
  for (int c = 0; c < 8; c++) {
    floatx4 z = {b1j[c], b1j[c], b1j[c], b1j[c]};
    acc[c] = __builtin_amdgcn_mfma_f32_16x16x32_bf16(
        af, *(const short8*)&w1f[(c * 64 + lane) * 8], z, 0, 0, 0);
  }

#pragma unroll
  for (int c = 0; c < 8; c++)
#pragma unroll
    for (int r = 0; r < 4; r += 2) {
      unsigned pk = f2bf2(fmaxf(acc[c][r], 0.f), fmaxf(acc[c][r + 1], 0.f));
      int base = (wv * 16 + quad * 4 + r) * ASP + c * 16 + l15;
      as_s[base] = (short)(pk & 0xffff);
      as_s[base + ASP] = (short)(pk >> 16);
    }

  floatx4 acc2[8];
#pragma unroll
  for (int c = 0; c < 8; c++) acc2[c] = (floatx4){b2j[c], b2j[c], b2j[c], b2j[c]};
#pragma unroll
  for (int s = 0; s < 4; s++) {
    short8 a2 = *(const short8*)&as_s[(wv * 16 + l15) * ASP + s * 32 + quad * 8];
#pragma unroll
    for (int c = 0; c < 8; c++) {
      short8 bf = *(const short8*)&w2f[((s * 8 + c) * 64 + lane) * 8];
      acc2[c] = __builtin_amdgcn_mfma_f32_16x16x32_bf16(a2, bf, acc2[c], 0, 0, 0);
    }
  }

  float p[2], qq[2], rr[2];
#pragma unroll
  for (int i = 0; i < 2; i++) { p[i] = 0.f; qq[i] = 0.f; rr[i] = 0.f; }
#pragma unroll
  for (int c = 0; c < 8; c++)
#pragma unroll
    for (int i = 0; i < 2; i++) {
      float hx = acc2[c][2 * i];
      float hy = acc2[c][2 * i + 1];
      p[i]  += hx * hy;
      qq[i] += hx * hx;
      rr[i] += hy * hy;
    }
#pragma unroll
  for (int m = 1; m < 16; m <<= 1)
#pragma unroll
    for (int i = 0; i < 2; i++) {
      p[i]  += __shfl_xor(p[i], m, 64);
      qq[i] += __shfl_xor(qq[i], m, 64);
      rr[i] += __shfl_xor(rr[i], m, 64);
    }
  if (l15 == 0) {
#pragma unroll
    for (int i = 0; i < 2; i++) {
      int row = rowbase + quad * 4 + 2 * i;
      int e = row >> 1;
      float n1 = fmaxf(sqrtf(qq[i]), 1e-8f);
      float n2 = fmaxf(sqrtf(rr[i]), 1e-8f);
      float w = (p[i] / (n1 * n2) + 1.f) * 0.5f;
      ew_out[e] = w;
      atomicAdd(deg + eidx[e], w);
      atomicAdd(cnt + eidx[EE + e], 1);
    }
  }
}

// ---------------- features fp32 -> bf16 ----------------
__global__ __launch_bounds__(256) void fconv_kernel(const float* __restrict__ src,
                                                    unsigned short* __restrict__ dst) {
  size_t i = ((size_t)blockIdx.x * 256 + threadIdx.x) * 8;
  float4 a = *(const float4*)(src + i);
  float4 b = *(const float4*)(src + i + 4);
  union { ushort8 s; unsigned u[4]; } o;
  o.u[0] = f2bf2(a.x, a.y); o.u[1] = f2bf2(a.z, a.w);
  o.u[2] = f2bf2(b.x, b.y); o.u[3] = f2bf2(b.z, b.w);
  *(ushort8*)(dst + i) = o.s;
}

// ---------------- weights: transpose 256x256 chunks, fp32 -> bf16 ----------------
__global__ __launch_bounds__(256) void wconv_kernel(
    const float* __restrict__ cheb_w, const float* __restrict__ cls_w1,
    unsigned short* __restrict__ wtc, unsigned short* __restrict__ clsT)
{
  __shared__ unsigned short tile[64][80];
  int z = blockIdx.z;
  const float* src; unsigned short* dst; int ldk;
  if (z < 12) {
    int l = z / 3, c = z % 3;
    src = cheb_w + (size_t)z * 65536;
    dst = wtc + (size_t)l * 196608 + c * 256;
    ldk = 768;
  } else {
    int c = z - 12;
    src = cls_w1 + (size_t)c * 65536;
    dst = clsT + c * 256;
    ldk = 1024;
  }
  int t = threadIdx.x;
  int k0 = blockIdx.x * 64, n0 = blockIdx.y * 64;
#pragma unroll
  for (int pass = 0; pass < 4; pass++) {
    int kk = pass * 16 + (t >> 4);
    int nl = (t & 15) * 4;
    float4 v = *(const float4*)(src + (size_t)(k0 + kk) * 256 + n0 + nl);
    tile[nl + 0][kk] = f2bf(v.x);
    tile[nl + 1][kk] = f2bf(v.y);
    tile[nl + 2][kk] = f2bf(v.z);
    tile[nl + 3][kk] = f2bf(v.w);
  }
  __syncthreads();
  int nl = t >> 2, kc = (t & 3) * 16;
  ushort8 v0 = *(const ushort8*)&tile[nl][kc];
  ushort8 v1 = *(const ushort8*)&tile[nl][kc + 8];
  unsigned short* dp = dst + (size_t)(n0 + nl) * ldk + k0 + kc;
  *(ushort8*)dp = v0;
  *(ushort8*)(dp + 8) = v1;
}

// ---------------- degree -> D^-1/2 ----------------
__global__ void dis_kernel(const float* __restrict__ deg, float* __restrict__ dis) {
  int i = blockIdx.x * 256 + threadIdx.x;
  if (i < NN) {
    float d = deg[i];
    dis[i] = d > 0.f ? 1.f / sqrtf(fmaxf(d, 1e-30f)) : 0.f;
  }
}

// ---------------- exclusive scan of in-degree counts (padded to x4) ----------------
__global__ __launch_bounds__(1024) void scan_kernel(const int* __restrict__ cnt, int* __restrict__ ptr) {
  __shared__ int sums[1024];
  int tid = threadIdx.x;
  const int n = NN;
  const int chunk = (n + 1023) / 1024;
  int base = tid * chunk;
  int s = 0;
  for (int i = 0; i < chunk; i++) {
    int idx = base + i;
    if (idx < n) s += (cnt[idx] + 3) & ~3;
  }
  sums[tid] = s;
  __syncthreads();
  for (int off = 1; off < 1024; off <<= 1) {
    int v = (tid >= off) ? sums[tid - off] : 0;
    __syncthreads();
    sums[tid] += v;
    __syncthreads();
  }
  int run = (tid == 0) ? 0 : sums[tid - 1];
  for (int i = 0; i < chunk; i++) {
    int idx = base + i;
    if (idx < n) { ptr[idx] = run; run += (cnt[idx] + 3) & ~3; }
  }
  if (tid == 1023) ptr[n] = run;
}

// ---------------- CSR fill (pad slots pre-zeroed) ----------------
__global__ void fill_kernel(const int* __restrict__ eidx, const float* __restrict__ ew,
                            const float* __restrict__ dis, const int* __restrict__ ptr,
                            int* __restrict__ fill, int* __restrict__ cidx, float* __restrict__ cval) {
  int e = blockIdx.x * 256 + threadIdx.x;
  if (e < EE) {
    int r = eidx[e], c = eidx[EE + e];
    float nv = -dis[r] * ew[e] * dis[c];
    int pos = ptr[c] + atomicAdd(&fill[c], 1);
    cidx[pos] = r;
    cval[pos] = nv;
  }
}

// ---------------- sparse prop (bf16, XCD-sliced, software-pipelined) ----------------
// y[c] = alpha*sum val*x[row] (- sub[c]). Column slice = (blockIdx&7)>>1 (64ch = 128B).
// 8 lanes per node. Segments padded to x4. 2-stage pipeline: next iteration's
// cidx/cval/gathers issued before current accumulate.
__global__ __launch_bounds__(256) void prop_kernel(
    const unsigned short* __restrict__ x, int ldx,
    const int* __restrict__ cidx, const float* __restrict__ cval,
    const int* __restrict__ ptr,
    unsigned short* __restrict__ y, int ldy,
    float alpha, const unsigned short* __restrict__ sub, int ldsub)
{
  int sliceid = blockIdx.x & 7;
  int colslice = sliceid >> 1;                       // 0..3
  int chunk = (blockIdx.x >> 3) * 2 + (sliceid & 1); // 0..625
  int c = chunk * 32 + (threadIdx.x >> 3);
  if (c >= NN) return;
  int d = colslice * 64 + (threadIdx.x & 7) * 8;
  int p0 = ptr[c], p1 = ptr[c + 1];
  float a[8] = {0.f, 0.f, 0.f, 0.f, 0.f, 0.f, 0.f, 0.f};
  if (p0 < p1) {
    int4 r4 = *(const int4*)(cidx + p0);
    float4 w4 = *(const float4*)(cval + p0);
    ushort8 v0 = *(const ushort8*)(x + (size_t)r4.x * ldx + d);
    ushort8 v1 = *(const ushort8*)(x + (size_t)r4.y * ldx + d);
    ushort8 v2 = *(const ushort8*)(x + (size_t)r4.z * ldx + d);
    ushort8 v3 = *(const ushort8*)(x + (size_t)r4.w * ldx + d);
    for (int p = p0 + 4; p < p1; p += 4) {
      int4 r4n = *(const int4*)(cidx + p);
      float4 w4n = *(const float4*)(cval + p);
      ushort8 n0 = *(const ushort8*)(x + (size_t)r4n.x * ldx + d);
      ushort8 n1 = *(const ushort8*)(x + (size_t)r4n.y * ldx + d);
      ushort8 n2 = *(const ushort8*)(x + (size_t)r4n.z * ldx + d);
      ushort8 n3 = *(const ushort8*)(x + (size_t)r4n.w * ldx + d);
#pragma unroll
      for (int j = 0; j < 8; j++)
        a[j] += w4.x * bf2f(v0[j]) + w4.y * bf2f(v1[j]) + w4.z * bf2f(v2[j]) + w4.w * bf2f(v3[j]);
      w4 = w4n; v0 = n0; v1 = n1; v2 = n2; v3 = n3;
    }
#pragma unroll
    for (int j = 0; j < 8; j++)
      a[j] += w4.x * bf2f(v0[j]) + w4.y * bf2f(v1[j]) + w4.z * bf2f(v2[j]) + w4.w * bf2f(v3[j]);
  }
  union { ushort8 s; unsigned u[4]; } o;
  if (sub) {
    ushort8 sv = *(const ushort8*)(sub + (size_t)c * ldsub + d);
#pragma unroll
    for (int j = 0; j < 8; j += 2)
      o.u[j >> 1] = f2bf2(alpha * a[j] - bf2f(sv[j]), alpha * a[j + 1] - bf2f(sv[j + 1]));
  } else {
#pragma unroll
    for (int j = 0; j < 8; j += 2)
      o.u[j >> 1] = f2bf2(a[j], a[j + 1]);
  }
  *(ushort8*)(y + (size_t)c * ldy + d) = o.s;
}

// ---------------- bf16 MFMA GEMM: C = post( sum_c A_c @ B_c ) ----------------
// launch_bounds(256,4): 12 KB LDS -> let 4+ blocks/CU co-reside to hide barrier drains
__global__ __launch_bounds__(256, 4) void mgemm_kernel(
    const unsigned short* A0, const unsigned short* A1,
    const unsigned short* A2, const unsigned short* A3,
    int l0, int l1, int l2, int l3, int nchunks,
    const unsigned short* __restrict__ BT, int ldbt,
    unsigned short* __restrict__ Cb, float* __restrict__ Cf, int ldc, int M,
    const float* __restrict__ bias, const float* __restrict__ bng,
    const float* __restrict__ bnb)
{
  __shared__ short As[4 * 64 * 8];
  __shared__ short Bs[4 * 128 * 8];
  int tid = threadIdx.x;
  int lane = tid & 63;
  int wv = tid >> 6;
  int l15 = lane & 15, quad = lane >> 4;
  int wr = wv >> 1, wc = wv & 1;
  int m0 = blockIdx.x * 64, n0 = blockIdx.y * 128;

  const unsigned short* Ap[4] = {A0, A1, A2, A3};
  int Al[4] = {l0, l1, l2, l3};

  int arow = tid & 63, ac = tid >> 6;
  int brow = tid & 127, bc = tid >> 7;

  floatx4 acc[2][4];
#pragma unroll
  for (int mi = 0; mi < 2; mi++)
#pragma unroll
    for (int nj = 0; nj < 4; nj++) acc[mi][nj] = (floatx4){0.f, 0.f, 0.f, 0.f};

  for (int c = 0; c < nchunks; c++) {
    const unsigned short* Abase = Ap[c] + (size_t)(m0 + arow) * Al[c] + ac * 8;
    const unsigned short* Bbase = BT + (size_t)(n0 + brow) * ldbt + c * 256 + bc * 8;
#pragma unroll 1
    for (int kb = 0; kb < 256; kb += 32) {
      __syncthreads();
      gl_lds16(Abase + kb, &As[tid * 8]);
      gl_lds16(Bbase + kb, &Bs[tid * 8]);
      gl_lds16(Bbase + 16 + kb, &Bs[(tid + 256) * 8]);
      __syncthreads();
      short8 af[2], bfv[4];
#pragma unroll
      for (int mi = 0; mi < 2; mi++)
        af[mi] = *(const short8*)&As[(quad * 64 + wr * 32 + mi * 16 + l15) * 8];
#pragma unroll
      for (int nj = 0; nj < 4; nj++)
        bfv[nj] = *(const short8*)&Bs[(quad * 128 + wc * 64 + nj * 16 + l15) * 8];
#pragma unroll
      for (int nj = 0; nj < 4; nj++)
#pragma unroll
        for (int mi = 0; mi < 2; mi++)
          acc[mi][nj] = __builtin_amdgcn_mfma_f32_16x16x32_bf16(af[mi], bfv[nj], acc[mi][nj], 0, 0, 0);
    }
  }

  if (Cb) {
#pragma unroll
    for (int mi = 0; mi < 2; mi++)
#pragma unroll
      for (int r = 0; r < 4; r++) {
        int row = m0 + wr * 32 + mi * 16 + quad * 4 + r;
        if (row < M) {
#pragma unroll
          for (int nj = 0; nj < 4; nj++) {
            int col = n0 + wc * 64 + nj * 16 + l15;
            Cb[(size_t)row * ldc + col] = (unsigned short)f2bf(fmaxf(acc[mi][nj][r], 0.f));
          }
        }
      }
  } else {
    float bs[4], g[4], bb[4];
#pragma unroll
    for (int nj = 0; nj < 4; nj++) {
      int col = n0 + wc * 64 + nj * 16 + l15;
      bs[nj] = bias[col]; g[nj] = bng[col] * RSBN; bb[nj] = bnb[col];
    }
#pragma unroll
    for (int mi = 0; mi < 2; mi++)
#pragma unroll
      for (int r = 0; r < 4; r++) {
        int row = m0 + wr * 32 + mi * 16 + quad * 4 + r;
        if (row < M) {
#pragma unroll
          for (int nj = 0; nj < 4; nj++) {
            int col = n0 + wc * 64 + nj * 16 + l15;
            float v = fmaxf(acc[mi][nj][r] + bs[nj], 0.f) * g[nj] + bb[nj];
            Cf[(size_t)row * ldc + col] = v;
          }
        }
      }
  }
}

// ---------------- final 256x2 matvec per node ----------------
__global__ __launch_bounds__(256) void logit_kernel(
    const float* __restrict__ z, const float* __restrict__ w2,
    const float* __restrict__ b2, float* __restrict__ out)
{
  int node = blockIdx.x * 4 + (threadIdx.x >> 6);
  if (node >= NN) return;
  int lane = threadIdx.x & 63;
  int k = lane * 4;
  float4 zv = *(const float4*)(z + (size_t)node * 256 + k);
  float4 wa = *(const float4*)(w2 + k * 2);
  float4 wb = *(const float4*)(w2 + k * 2 + 4);
  float a0 = zv.x * wa.x + zv.y * wa.z + zv.z * wb.x + zv.w * wb.z;
  float a1 = zv.x * wa.y + zv.y * wa.w + zv.z * wb.y + zv.w * wb.w;
#pragma unroll
  for (int m = 32; m >= 1; m >>= 1) {
    a0 += __shfl_xor(a0, m, 64);
    a1 += __shfl_xor(a1, m, 64);
  }
  if (lane == 0) {
    out[(size_t)node * 2]     = a0 + b2[0];
    out[(size_t)node * 2 + 1] = a1 + b2[1];
  }
}

extern "C" void kernel_launch(void* const* d_in, const int* in_sizes, int n_in,
                              void* d_out, int out_size, void* d_ws, size_t ws_size,
                              hipStream_t stream) {
  const float* features = (const float*)d_in[0];
  const int*   eidx     = (const int*)d_in[1];
  const float* xin      = (const float*)d_in[2];
  const float* cheb_w   = (const float*)d_in[3];
  const float* en_w1    = (const float*)d_in[4];
  const float* en_b1    = (const float*)d_in[5];
  const float* en_g1    = (const float*)d_in[6];
  const float* en_be1   = (const float*)d_in[7];
  const float* en_w2    = (const float*)d_in[8];
  const float* en_b2    = (const float*)d_in[9];
  const float* cls_w1   = (const float*)d_in[10];
  const float* cls_b1   = (const float*)d_in[11];
  const float* cls_g    = (const float*)d_in[12];
  const float* cls_b    = (const float*)d_in[13];
  const float* cls_w2   = (const float*)d_in[14];
  const float* cls_b2   = (const float*)d_in[15];
  float* out = (float*)d_out;

  char* ws = (char*)d_ws;
  size_t off = 0;
  auto alloc = [&](size_t bytes) -> void* {
    void* p = ws + off;
    off += (bytes + 255) & ~(size_t)255;
    return p;
  };
  const int CSRN = EE + 4 * NN;   // padded CSR capacity
  float* deg  = (float*)alloc((size_t)NN * 4);
  int*   cnt  = (int*)  alloc((size_t)NN * 4);
  int*   fil  = (int*)  alloc((size_t)NN * 4);
  float* cval = (float*)alloc((size_t)CSRN * 4);
  int*   cidx = (int*)  alloc((size_t)CSRN * 4);
  size_t zero_len = off;                       // deg+cnt+fil+cval+cidx zeroed
  float* dis  = (float*)alloc((size_t)NN * 4);
  int*   ptr  = (int*)  alloc((size_t)(NN + 1) * 4);
  unsigned short* featb = (unsigned short*)alloc((size_t)NN * 256 * 2);
  unsigned short* Tx1   = (unsigned short*)alloc((size_t)NN * 256 * 2);
  unsigned short* Tx2   = (unsigned short*)alloc((size_t)NN * 256 * 2);
  unsigned short* jk    = (unsigned short*)alloc((size_t)NN * 1024 * 2);
  float* zbuf = (float*)alloc((size_t)NN * 256 * 4);
  unsigned short* wtc   = (unsigned short*)alloc((size_t)4 * 196608 * 2);
  unsigned short* clsT  = (unsigned short*)alloc((size_t)256 * 1024 * 2);
  unsigned short* ewf   = (unsigned short*)alloc((size_t)20992 * 2);
  alloc(262144);   // overread pad for GEMM tail blocks

  float* ew = out + (size_t)NN * 2;   // edge-weight output doubles as scratch

  hipMemsetAsync(deg, 0, zero_len, stream);

  ewconv_kernel<<<1, 256, 0, stream>>>(en_w1, en_w2, en_g1, en_be1, en_b1, en_b2, ewf);
  edge_kernel<<<6250, 512, 0, stream>>>(xin, eidx, ewf, ew, deg, cnt);
  fconv_kernel<<<2500, 256, 0, stream>>>(features, featb);
  wconv_kernel<<<dim3(4, 4, 16), 256, 0, stream>>>(cheb_w, cls_w1, wtc, clsT);
  dis_kernel<<<(NN + 255) / 256, 256, 0, stream>>>(deg, dis);
  scan_kernel<<<1, 1024, 0, stream>>>(cnt, ptr);
  fill_kernel<<<(EE + 255) / 256, 256, 0, stream>>>(eidx, ew, dis, ptr, fil, cidx, cval);

  dim3 ggrid(313, 2);
  for (int i = 0; i < 4; i++) {
    const unsigned short* x = (i == 0) ? featb : (jk + (size_t)(i - 1) * 256);
    int ldx = (i == 0) ? 256 : 1024;
    prop_kernel<<<2504, 256, 0, stream>>>(x, ldx, cidx, cval, ptr, Tx1, 256, 1.f, nullptr, 0);
    prop_kernel<<<2504, 256, 0, stream>>>(Tx1, 256, cidx, cval, ptr, Tx2, 256, 2.f, x, ldx);
    mgemm_kernel<<<ggrid, 256, 0, stream>>>(x, Tx1, Tx2, nullptr, ldx, 256, 256, 0, 3,
                                            wtc + (size_t)i * 196608, 768,
                                            jk + (size_t)i * 256, nullptr, 1024, NN,
                                            nullptr, nullptr, nullptr);
  }

  mgemm_kernel<<<ggrid, 256, 0, stream>>>(jk, jk + 256, jk + 512, jk + 768,
                                          1024, 1024, 1024, 1024, 4, clsT, 1024,
                                          nullptr, zbuf, 256, NN,
                                          cls_b1, cls_g, cls_b);
  logit_kernel<<<NN / 4, 256, 0, stream>>>(zbuf, cls_w2, cls_b2, out);
}